// Round 1
// baseline (1246.222 us; speedup 1.0000x reference)
//
#include <hip/hip_runtime.h>
#include <math.h>

#define B_ 128
#define S_ 256
#define V_ 50000
#define E_ 300
#define D_ 200
#define C_ 3
#define P_ 256            // padded D
#define TOK_ (B_*S_)      // 32768

// ---------------- pad / zero kernels ----------------
__global__ void pad2d_kernel(const float* __restrict__ src, float* __restrict__ dst,
                             int sR, int sC, int dR, int dC) {
  int idx = blockIdx.x * 256 + threadIdx.x;
  if (idx >= dR * dC) return;
  int r = idx / dC, c = idx - r * dC;
  dst[idx] = (r < sR && c < sC) ? src[r * sC + c] : 0.0f;
}

// src [400][200] -> dst [512][256]; input layout [x(256 padded) | y(256 padded)]
__global__ void padcat_kernel(const float* __restrict__ src, float* __restrict__ dst) {
  int idx = blockIdx.x * 256 + threadIdx.x;
  if (idx >= 512 * 256) return;
  int r = idx >> 8, c = idx & 255;
  int sr = (r < 200) ? r : ((r >= 256 && r < 456) ? (r - 56) : -1);
  dst[idx] = (sr >= 0 && c < 200) ? src[sr * 200 + c] : 0.0f;
}

__global__ void zero_kernel(float* __restrict__ p, int n) {
  int idx = blockIdx.x * 256 + threadIdx.x;
  if (idx < n) p[idx] = 0.0f;
}

// ---------------- per-token inverse embedding norm ----------------
__global__ __launch_bounds__(256) void invnorm_kernel(const int* __restrict__ ids,
    const float* __restrict__ emb, float* __restrict__ invn) {
  int tok = blockIdx.x * 4 + (threadIdx.x >> 6);
  int l = threadIdx.x & 63;
  long base = (long)ids[tok] * E_;
  float ss = 0.0f;
  for (int e = l; e < E_; e += 64) { float v = emb[base + e]; ss += v * v; }
  #pragma unroll
  for (int d = 32; d >= 1; d >>= 1) ss += __shfl_xor(ss, d, 64);
  if (l == 0) invn[tok] = 1.0f / sqrtf(ss);
}

// ---------------- generic fp32 GEMM:  out[M x 256] = act(A @ W + b) ----------------
// MODE 0: A = A1 [M][256]
// MODE 1: A row t = emb[ids[t]] * invn[t]   (K = 300, gather)
// MODE 2: A = concat(A1 [M][256], A2 [M][256])  (K = 512)
// AGG: masked atomic aggregation into aggOut[B][256] instead of writing rows
template<int MODE, bool RELU, bool AGG>
__global__ __launch_bounds__(256, 2) void gemm_kernel(
    const float* __restrict__ A1, const float* __restrict__ A2,
    const int* __restrict__ ids, const float* __restrict__ emb,
    const float* __restrict__ invn,
    const float* __restrict__ W, const float* __restrict__ bias,
    float* __restrict__ outp, float* __restrict__ aggOut,
    const int* __restrict__ lens, int K)
{
  __shared__ float As[64][36];     // 64 rows x 32 k (pad 36 to stagger banks)
  __shared__ float Bs[32][P_];     // 32 k x 256 cols
  const int tid = threadIdx.x;
  const long t0 = (long)blockIdx.x * 64;
  const int tr = tid >> 5;         // 0..7  (8 row groups of 8)
  const int tc = tid & 31;         // 0..31 (col base tc*4, +128)
  float acc[8][8];
  #pragma unroll
  for (int r = 0; r < 8; ++r)
    #pragma unroll
    for (int v = 0; v < 8; ++v) acc[r][v] = 0.0f;

  for (int k0 = 0; k0 < K; k0 += 32) {
    { // stage A tile
      int row = tid >> 3;
      const int k4 = (tid & 7) * 4;
      #pragma unroll
      for (int p = 0; p < 2; ++p, row += 32) {
        const long t = t0 + row;
        float4 v;
        if (MODE == 1) {
          const long base = (long)ids[t] * E_;
          const float inv = invn[t];
          const int kk = k0 + k4;
          v.x = (kk + 0 < K) ? emb[base + kk + 0] * inv : 0.0f;
          v.y = (kk + 1 < K) ? emb[base + kk + 1] * inv : 0.0f;
          v.z = (kk + 2 < K) ? emb[base + kk + 2] * inv : 0.0f;
          v.w = (kk + 3 < K) ? emb[base + kk + 3] * inv : 0.0f;
        } else if (MODE == 2) {
          const float* src = (k0 < P_) ? (A1 + t * P_ + k0) : (A2 + t * P_ + (k0 - P_));
          v = *(const float4*)(src + k4);
        } else {
          v = *(const float4*)(A1 + t * P_ + k0 + k4);
        }
        *(float4*)&As[row][k4] = v;
      }
    }
    { // stage B tile (W rows k0..k0+31)
      const int c4 = (tid & 63) * 4;
      int kk = tid >> 6;
      #pragma unroll
      for (int p = 0; p < 8; ++p, kk += 4) {
        float4 v;
        if (MODE == 1 && (k0 + kk) >= K) { v.x = v.y = v.z = v.w = 0.0f; }
        else v = *(const float4*)(W + (long)(k0 + kk) * P_ + c4);
        *(float4*)&Bs[kk][c4] = v;
      }
    }
    __syncthreads();
    #pragma unroll
    for (int kk = 0; kk < 32; kk += 4) {
      float4 a[8];
      #pragma unroll
      for (int r = 0; r < 8; ++r) a[r] = *(const float4*)&As[tr * 8 + r][kk];
      #pragma unroll
      for (int q = 0; q < 4; ++q) {
        const float4 b0 = *(const float4*)&Bs[kk + q][tc * 4];
        const float4 b1 = *(const float4*)&Bs[kk + q][tc * 4 + 128];
        #pragma unroll
        for (int r = 0; r < 8; ++r) {
          const float av = (q == 0) ? a[r].x : (q == 1) ? a[r].y : (q == 2) ? a[r].z : a[r].w;
          acc[r][0] += av * b0.x; acc[r][1] += av * b0.y;
          acc[r][2] += av * b0.z; acc[r][3] += av * b0.w;
          acc[r][4] += av * b1.x; acc[r][5] += av * b1.y;
          acc[r][6] += av * b1.z; acc[r][7] += av * b1.w;
        }
      }
    }
    __syncthreads();
  }
  const int c0 = tc * 4;
  float4 bb0, bb1;
  if (bias) { bb0 = *(const float4*)&bias[c0]; bb1 = *(const float4*)&bias[c0 + 128]; }
  else { bb0.x = bb0.y = bb0.z = bb0.w = 0.0f; bb1 = bb0; }
  if (AGG) {
    const int b = (int)(t0 / S_);
    const int s0 = (int)(t0 - (long)b * S_);
    const int len = lens[b];
    float sums[8] = {0,0,0,0,0,0,0,0};
    #pragma unroll
    for (int r = 0; r < 8; ++r) {
      if (s0 + tr * 8 + r < len) {
        sums[0] += fmaxf(acc[r][0] + bb0.x, 0.0f);
        sums[1] += fmaxf(acc[r][1] + bb0.y, 0.0f);
        sums[2] += fmaxf(acc[r][2] + bb0.z, 0.0f);
        sums[3] += fmaxf(acc[r][3] + bb0.w, 0.0f);
        sums[4] += fmaxf(acc[r][4] + bb1.x, 0.0f);
        sums[5] += fmaxf(acc[r][5] + bb1.y, 0.0f);
        sums[6] += fmaxf(acc[r][6] + bb1.z, 0.0f);
        sums[7] += fmaxf(acc[r][7] + bb1.w, 0.0f);
      }
    }
    #pragma unroll
    for (int j = 0; j < 4; ++j) atomicAdd(&aggOut[(long)b * P_ + c0 + j], sums[j]);
    #pragma unroll
    for (int j = 0; j < 4; ++j) atomicAdd(&aggOut[(long)b * P_ + c0 + 128 + j], sums[4 + j]);
  } else {
    #pragma unroll
    for (int r = 0; r < 8; ++r) {
      const long row = t0 + tr * 8 + r;
      float4 o0, o1;
      o0.x = acc[r][0] + bb0.x; o0.y = acc[r][1] + bb0.y;
      o0.z = acc[r][2] + bb0.z; o0.w = acc[r][3] + bb0.w;
      o1.x = acc[r][4] + bb1.x; o1.y = acc[r][5] + bb1.y;
      o1.z = acc[r][6] + bb1.z; o1.w = acc[r][7] + bb1.w;
      if (RELU) {
        o0.x = fmaxf(o0.x, 0.0f); o0.y = fmaxf(o0.y, 0.0f);
        o0.z = fmaxf(o0.z, 0.0f); o0.w = fmaxf(o0.w, 0.0f);
        o1.x = fmaxf(o1.x, 0.0f); o1.y = fmaxf(o1.y, 0.0f);
        o1.z = fmaxf(o1.z, 0.0f); o1.w = fmaxf(o1.w, 0.0f);
      }
      *(float4*)&outp[row * P_ + c0] = o0;
      *(float4*)&outp[row * P_ + c0 + 128] = o1;
    }
  }
}

// ---------------- sim = (f1 @ f2^T) * mask, per batch ----------------
__global__ __launch_bounds__(256, 2) void sim_kernel(
    const float* __restrict__ f1, const float* __restrict__ f2,
    const int* __restrict__ len1, const int* __restrict__ len2,
    float* __restrict__ simp)
{
  __shared__ float As[64][36];
  __shared__ float Bs[64][36];
  const int b = blockIdx.x;
  const int i0 = blockIdx.y * 64, j0 = blockIdx.z * 64;
  const float* Ap = f1 + ((long)b * S_ + i0) * P_;
  const float* Bp = f2 + ((long)b * S_ + j0) * P_;
  const int tid = threadIdx.x;
  float acc[4][4];
  #pragma unroll
  for (int r = 0; r < 4; ++r)
    #pragma unroll
    for (int c = 0; c < 4; ++c) acc[r][c] = 0.0f;
  const int ti = tid >> 4, tj = tid & 15;
  for (int k0 = 0; k0 < P_; k0 += 32) {
    int row = tid >> 3;
    const int k4 = (tid & 7) * 4;
    #pragma unroll
    for (int p = 0; p < 2; ++p, row += 32) {
      *(float4*)&As[row][k4] = *(const float4*)(Ap + (long)row * P_ + k0 + k4);
      *(float4*)&Bs[row][k4] = *(const float4*)(Bp + (long)row * P_ + k0 + k4);
    }
    __syncthreads();
    #pragma unroll
    for (int kk = 0; kk < 32; kk += 4) {
      float4 a[4], bb[4];
      #pragma unroll
      for (int r = 0; r < 4; ++r) a[r] = *(const float4*)&As[ti + 16 * r][kk];
      #pragma unroll
      for (int c = 0; c < 4; ++c) bb[c] = *(const float4*)&Bs[tj + 16 * c][kk];
      #pragma unroll
      for (int r = 0; r < 4; ++r)
        #pragma unroll
        for (int c = 0; c < 4; ++c)
          acc[r][c] += a[r].x * bb[c].x + a[r].y * bb[c].y + a[r].z * bb[c].z + a[r].w * bb[c].w;
    }
    __syncthreads();
  }
  const int l1 = len1[b], l2 = len2[b];
  #pragma unroll
  for (int r = 0; r < 4; ++r) {
    const int i = i0 + ti + 16 * r;
    const float mi = (i < l1) ? 1.0f : 0.0f;
    #pragma unroll
    for (int c = 0; c < 4; ++c) {
      const int j = j0 + tj + 16 * c;
      const float m = (j < l2) ? mi : 0.0f;
      simp[(long)b * S_ * S_ + (long)i * S_ + j] = acc[r][c] * m;
    }
  }
}

// ---------------- softmax (row or col of sim) + weighted sum over X ----------------
// COL=false: out[b,i,:] = softmax_j(sim[b,i,:]) @ X[b,:,:]   (beta,  X = x2p)
// COL=true : out[b,j,:] = softmax_i(sim[b,:,j])^T @ X[b,:,:] (alpha, X = x1p)
template<bool COL>
__global__ __launch_bounds__(256) void attend_kernel(
    const float* __restrict__ simp, const float* __restrict__ X,
    float* __restrict__ outp)
{
  __shared__ float ps[8][S_];
  const int b = blockIdx.x;
  const int r0 = blockIdx.y * 8;
  const int tid = threadIdx.x;
  const float* M = simp + (long)b * S_ * S_;
  {
    const int r = tid >> 5, l = tid & 31;
    const int rr = r0 + r;
    float v[8];
    #pragma unroll
    for (int k = 0; k < 8; ++k) {
      const int idx = l + 32 * k;
      v[k] = COL ? M[(long)idx * S_ + rr] : M[(long)rr * S_ + idx];
    }
    float m = v[0];
    #pragma unroll
    for (int k = 1; k < 8; ++k) m = fmaxf(m, v[k]);
    #pragma unroll
    for (int d = 16; d >= 1; d >>= 1) m = fmaxf(m, __shfl_xor(m, d, 32));
    float sum = 0.0f;
    #pragma unroll
    for (int k = 0; k < 8; ++k) { v[k] = expf(v[k] - m); sum += v[k]; }
    #pragma unroll
    for (int d = 16; d >= 1; d >>= 1) sum += __shfl_xor(sum, d, 32);
    const float inv = 1.0f / sum;
    #pragma unroll
    for (int k = 0; k < 8; ++k) ps[r][l + 32 * k] = v[k] * inv;
  }
  __syncthreads();
  float acc[8] = {0,0,0,0,0,0,0,0};
  const float* Xb = X + (long)b * S_ * P_;
  for (int j = 0; j < S_; j += 4) {
    const float x0 = Xb[(long)(j + 0) * P_ + tid];
    const float x1 = Xb[(long)(j + 1) * P_ + tid];
    const float x2 = Xb[(long)(j + 2) * P_ + tid];
    const float x3 = Xb[(long)(j + 3) * P_ + tid];
    #pragma unroll
    for (int r = 0; r < 8; ++r) {
      const float4 p4 = *(const float4*)&ps[r][j];
      acc[r] += p4.x * x0 + p4.y * x1 + p4.z * x2 + p4.w * x3;
    }
  }
  #pragma unroll
  for (int r = 0; r < 8; ++r)
    outp[((long)b * S_ + r0 + r) * P_ + tid] = acc[r];
}

// ---------------- final head: y = relu(relu([v1|v2]@HW1+b1)@HW2+b2)@Wout+bout ----------------
__global__ __launch_bounds__(256) void head_kernel(
    const float* __restrict__ v1s, const float* __restrict__ v2s,
    const float* __restrict__ HW1p, const float* __restrict__ Hb1p,
    const float* __restrict__ HW2p, const float* __restrict__ Hb2p,
    const float* __restrict__ Wout, const float* __restrict__ bout,
    float* __restrict__ y)
{
  __shared__ float xin[2 * P_];
  __shared__ float h[P_];
  const int b = blockIdx.x;
  const int tid = threadIdx.x;
  xin[tid] = v1s[(long)b * P_ + tid];
  xin[P_ + tid] = v2s[(long)b * P_ + tid];
  __syncthreads();
  float acc = Hb1p[tid];
  for (int e = 0; e < 2 * P_; ++e) acc += xin[e] * HW1p[(long)e * P_ + tid];
  h[tid] = fmaxf(acc, 0.0f);
  __syncthreads();
  float acc2 = Hb2p[tid];
  for (int e = 0; e < P_; ++e) acc2 += h[e] * HW2p[(long)e * P_ + tid];
  const float h2 = fmaxf(acc2, 0.0f);
  __syncthreads();
  xin[tid] = h2;
  __syncthreads();
  if (tid < C_) {
    float a = bout[tid];
    for (int d = 0; d < D_; ++d) a += xin[d] * Wout[d * C_ + tid];
    y[(long)b * C_ + tid] = a;
  }
}

// ---------------- launch ----------------
extern "C" void kernel_launch(void* const* d_in, const int* in_sizes, int n_in,
                              void* d_out, int out_size, void* d_ws, size_t ws_size,
                              hipStream_t stream)
{
  const int*   x1    = (const int*)d_in[0];
  const int*   x2    = (const int*)d_in[1];
  const int*   len1  = (const int*)d_in[2];
  const int*   len2  = (const int*)d_in[3];
  const float* emb   = (const float*)d_in[4];
  const float* Wproj = (const float*)d_in[5];
  const float* FW1   = (const float*)d_in[6];
  const float* Fb1   = (const float*)d_in[7];
  const float* FW2   = (const float*)d_in[8];
  const float* Fb2   = (const float*)d_in[9];
  const float* GW1   = (const float*)d_in[10];
  const float* Gb1   = (const float*)d_in[11];
  const float* GW2   = (const float*)d_in[12];
  const float* Gb2   = (const float*)d_in[13];
  const float* HW1   = (const float*)d_in[14];
  const float* Hb1   = (const float*)d_in[15];
  const float* HW2   = (const float*)d_in[16];
  const float* Hb2   = (const float*)d_in[17];
  const float* Wout  = (const float*)d_in[18];
  const float* bout  = (const float*)d_in[19];
  float* out = (float*)d_out;

  float* ws = (float*)d_ws;
  size_t o = 0;
  auto alloc = [&](size_t n) { float* p = ws + o; o += n; return p; };
  float* x1p   = alloc((size_t)TOK_ * P_);
  float* x2p   = alloc((size_t)TOK_ * P_);
  float* f1    = alloc((size_t)TOK_ * P_);   // later reused as beta
  float* f2    = alloc((size_t)TOK_ * P_);   // later reused as alpha
  float* hid   = alloc((size_t)TOK_ * P_);
  float* simb  = alloc((size_t)B_ * S_ * S_);
  float* v1s   = alloc((size_t)B_ * P_);
  float* v2s   = alloc((size_t)B_ * P_);     // contiguous after v1s (zeroed together)
  float* invn1 = alloc(TOK_);
  float* invn2 = alloc(TOK_);
  float* Wpp   = alloc((size_t)E_ * P_);
  float* FW1p  = alloc((size_t)P_ * P_); float* Fb1p = alloc(P_);
  float* FW2p  = alloc((size_t)P_ * P_); float* Fb2p = alloc(P_);
  float* GW1p  = alloc((size_t)2 * P_ * P_); float* Gb1p = alloc(P_);
  float* GW2p  = alloc((size_t)P_ * P_); float* Gb2p = alloc(P_);
  float* HW1p  = alloc((size_t)2 * P_ * P_); float* Hb1p = alloc(P_);
  float* HW2p  = alloc((size_t)P_ * P_); float* Hb2p = alloc(P_);
  if (o * sizeof(float) > ws_size) return;   // workspace too small; bail loudly

  auto g = [](int n) { return (n + 255) / 256; };

  // --- weight padding / init ---
  pad2d_kernel<<<g(E_ * P_), 256, 0, stream>>>(Wproj, Wpp, E_, D_, E_, P_);
  pad2d_kernel<<<g(P_ * P_), 256, 0, stream>>>(FW1, FW1p, D_, D_, P_, P_);
  pad2d_kernel<<<g(P_ * P_), 256, 0, stream>>>(FW2, FW2p, D_, D_, P_, P_);
  pad2d_kernel<<<g(P_ * P_), 256, 0, stream>>>(GW2, GW2p, D_, D_, P_, P_);
  pad2d_kernel<<<g(P_ * P_), 256, 0, stream>>>(HW2, HW2p, D_, D_, P_, P_);
  padcat_kernel<<<g(2 * P_ * P_), 256, 0, stream>>>(GW1, GW1p);
  padcat_kernel<<<g(2 * P_ * P_), 256, 0, stream>>>(HW1, HW1p);
  pad2d_kernel<<<1, 256, 0, stream>>>(Fb1, Fb1p, 1, D_, 1, P_);
  pad2d_kernel<<<1, 256, 0, stream>>>(Fb2, Fb2p, 1, D_, 1, P_);
  pad2d_kernel<<<1, 256, 0, stream>>>(Gb1, Gb1p, 1, D_, 1, P_);
  pad2d_kernel<<<1, 256, 0, stream>>>(Gb2, Gb2p, 1, D_, 1, P_);
  pad2d_kernel<<<1, 256, 0, stream>>>(Hb1, Hb1p, 1, D_, 1, P_);
  pad2d_kernel<<<1, 256, 0, stream>>>(Hb2, Hb2p, 1, D_, 1, P_);
  zero_kernel<<<g(2 * B_ * P_), 256, 0, stream>>>(v1s, 2 * B_ * P_);

  // --- embedding norms + projection GEMMs (gathered) ---
  invnorm_kernel<<<TOK_ / 4, 256, 0, stream>>>(x1, emb, invn1);
  invnorm_kernel<<<TOK_ / 4, 256, 0, stream>>>(x2, emb, invn2);
  gemm_kernel<1, false, false><<<TOK_ / 64, 256, 0, stream>>>(
      nullptr, nullptr, x1, emb, invn1, Wpp, nullptr, x1p, nullptr, nullptr, E_);
  gemm_kernel<1, false, false><<<TOK_ / 64, 256, 0, stream>>>(
      nullptr, nullptr, x2, emb, invn2, Wpp, nullptr, x2p, nullptr, nullptr, E_);

  // --- F MLP (both sequences) ---
  gemm_kernel<0, true, false><<<TOK_ / 64, 256, 0, stream>>>(
      x1p, nullptr, nullptr, nullptr, nullptr, FW1p, Fb1p, hid, nullptr, nullptr, P_);
  gemm_kernel<0, true, false><<<TOK_ / 64, 256, 0, stream>>>(
      hid, nullptr, nullptr, nullptr, nullptr, FW2p, Fb2p, f1, nullptr, nullptr, P_);
  gemm_kernel<0, true, false><<<TOK_ / 64, 256, 0, stream>>>(
      x2p, nullptr, nullptr, nullptr, nullptr, FW1p, Fb1p, hid, nullptr, nullptr, P_);
  gemm_kernel<0, true, false><<<TOK_ / 64, 256, 0, stream>>>(
      hid, nullptr, nullptr, nullptr, nullptr, FW2p, Fb2p, f2, nullptr, nullptr, P_);

  // --- similarity + mask ---
  {
    dim3 grid(B_, S_ / 64, S_ / 64);
    sim_kernel<<<grid, 256, 0, stream>>>(f1, f2, len1, len2, simb);
  }

  // --- softmax-weighted sums (beta overwrites f1, alpha overwrites f2) ---
  {
    dim3 grid(B_, S_ / 8);
    attend_kernel<false><<<grid, 256, 0, stream>>>(simb, x2p, f1);  // beta
    attend_kernel<true ><<<grid, 256, 0, stream>>>(simb, x1p, f2);  // alpha
  }

  // --- G MLP + masked aggregation ---
  gemm_kernel<2, true, false><<<TOK_ / 64, 256, 0, stream>>>(
      x1p, f1, nullptr, nullptr, nullptr, GW1p, Gb1p, hid, nullptr, nullptr, 2 * P_);
  gemm_kernel<0, true, true><<<TOK_ / 64, 256, 0, stream>>>(
      hid, nullptr, nullptr, nullptr, nullptr, GW2p, Gb2p, nullptr, v1s, len1, P_);
  gemm_kernel<2, true, false><<<TOK_ / 64, 256, 0, stream>>>(
      x2p, f2, nullptr, nullptr, nullptr, GW1p, Gb1p, hid, nullptr, nullptr, 2 * P_);
  gemm_kernel<0, true, true><<<TOK_ / 64, 256, 0, stream>>>(
      hid, nullptr, nullptr, nullptr, nullptr, GW2p, Gb2p, nullptr, v2s, len2, P_);

  // --- head ---
  head_kernel<<<B_, 256, 0, stream>>>(v1s, v2s, HW1p, Hb1p, HW2p, Hb2p, Wout, bout, out);
}

// Round 3
// 621.610 us; speedup vs baseline: 2.0048x; 2.0048x over previous
//
#include <hip/hip_runtime.h>
#include <math.h>

#define B_ 128
#define S_ 256
#define V_ 50000
#define E_ 300
#define D_ 200
#define C_ 3
#define P_ 256            // padded D
#define TOK_ (B_*S_)      // 32768

typedef __attribute__((ext_vector_type(8))) short bf16x8;
typedef __attribute__((ext_vector_type(4))) float f32x4;

static __device__ __forceinline__ short f2bf(float f) {
  unsigned u = __builtin_bit_cast(unsigned, f);
  u += 0x7fffu + ((u >> 16) & 1u);   // RNE
  return (short)(u >> 16);
}
static __device__ __forceinline__ float bf2f(unsigned short u) {
  unsigned v = ((unsigned)u) << 16;
  return __builtin_bit_cast(float, v);
}

// ---------------- pad / zero kernels (fp32, for head weights + biases) ----------------
__global__ void pad2d_kernel(const float* __restrict__ src, float* __restrict__ dst,
                             int sR, int sC, int dR, int dC) {
  int idx = blockIdx.x * 256 + threadIdx.x;
  if (idx >= dR * dC) return;
  int r = idx / dC, c = idx - r * dC;
  dst[idx] = (r < sR && c < sC) ? src[r * sC + c] : 0.0f;
}

// src [400][200] -> dst [512][256] fp32 (for HW1)
__global__ void padcat_kernel(const float* __restrict__ src, float* __restrict__ dst) {
  int idx = blockIdx.x * 256 + threadIdx.x;
  if (idx >= 512 * 256) return;
  int r = idx >> 8, c = idx & 255;
  int sr = (r < 200) ? r : ((r >= 256 && r < 456) ? (r - 56) : -1);
  dst[idx] = (sr >= 0 && c < 200) ? src[sr * 200 + c] : 0.0f;
}

// transpose-pad to bf16: dst[n][k] = src[k][n], dst [dN][dK]
__global__ void padT_bf16(const float* __restrict__ src, unsigned short* __restrict__ dst,
                          int sK, int sN, int dK, int dN) {
  int idx = blockIdx.x * 256 + threadIdx.x;
  if (idx >= dN * dK) return;
  int n = idx / dK, k = idx - n * dK;
  float v = (k < sK && n < sN) ? src[k * sN + n] : 0.0f;
  dst[idx] = (unsigned short)f2bf(v);
}

// GW1 [400][200] -> GW1T bf16 [256][512]; k<256 -> x-part rows 0..199, k>=256 -> second part
__global__ void padcatT_bf16(const float* __restrict__ src, unsigned short* __restrict__ dst) {
  int idx = blockIdx.x * 256 + threadIdx.x;
  if (idx >= 256 * 512) return;
  int n = idx >> 9, k = idx & 511;
  int sk = (k < 256) ? ((k < 200) ? k : -1) : (((k - 256) < 200) ? (200 + k - 256) : -1);
  float v = (sk >= 0 && n < 200) ? src[sk * 200 + n] : 0.0f;
  dst[idx] = (unsigned short)f2bf(v);
}

__global__ void zero_kernel(float* __restrict__ p, int n) {
  int idx = blockIdx.x * 256 + threadIdx.x;
  if (idx < n) p[idx] = 0.0f;
}

// ---------------- per-token inverse embedding norm ----------------
__global__ __launch_bounds__(256) void invnorm_kernel(const int* __restrict__ ids,
    const float* __restrict__ emb, float* __restrict__ invn) {
  int tok = blockIdx.x * 4 + (threadIdx.x >> 6);
  int l = threadIdx.x & 63;
  long base = (long)ids[tok] * E_;
  float ss = 0.0f;
  for (int e = l; e < E_; e += 64) { float v = emb[base + e]; ss += v * v; }
  #pragma unroll
  for (int d = 32; d >= 1; d >>= 1) ss += __shfl_xor(ss, d, 64);
  if (l == 0) invn[tok] = 1.0f / sqrtf(ss);
}

// ---------------- bf16 MFMA GEMM: out[M x 256] = act(A @ W + b) ----------------
// Tile: 128 rows x 256 cols, 512 threads (8 waves, 2x4), BK=32.
// MODE 0: A = A1 bf16 [M][256]
// MODE 1: A row t = bf16(emb[ids[t]] * invn[t])  (K=320 padded, valid k<300)
// MODE 2: A = concat(A1 [M][256], A2 [M][256]) bf16  (K=512)
// WT: bf16 [256][K]  (W transposed)
// AGG: masked (lens) sum of relu rows -> atomicAdd into aggOut[B][256] fp32
template<int MODE, bool RELU, bool AGG>
__global__ __launch_bounds__(512) void gemm_mfma(
    const unsigned short* __restrict__ A1, const unsigned short* __restrict__ A2,
    const int* __restrict__ ids, const float* __restrict__ emb,
    const float* __restrict__ invn,
    const unsigned short* __restrict__ WT, const float* __restrict__ bias,
    unsigned short* __restrict__ outp, float* __restrict__ aggOut,
    const int* __restrict__ lens, int K)
{
  __shared__ unsigned short As[128 * 32];   // swizzled: 16B slot = kslot ^ ((row>>1)&3)
  __shared__ unsigned short Bs[256 * 32];
  const int tid = threadIdx.x;
  const int lane = tid & 63;
  const int w = tid >> 6;
  const int wr = w >> 2, wc = w & 3;
  const long t0 = (long)blockIdx.x * 128;
  const int g = lane >> 4, ln = lane & 15;

  f32x4 acc[4][4];
  #pragma unroll
  for (int i = 0; i < 4; ++i)
    #pragma unroll
    for (int j = 0; j < 4; ++j) acc[i][j] = (f32x4){0.f, 0.f, 0.f, 0.f};

  const int arow = tid >> 2, aks = tid & 3;

  for (int k0 = 0; k0 < K; k0 += 32) {
    // ---- stage A tile [128][32]
    {
      bf16x8 v;
      if (MODE == 1) {
        const long t = t0 + arow;
        const long base = (long)ids[t] * E_;
        const float inv = invn[t];
        const int kb = k0 + aks * 8;
        short tmp[8];
        #pragma unroll
        for (int i = 0; i < 8; ++i) {
          const int k = kb + i;
          tmp[i] = f2bf((k < E_) ? emb[base + k] * inv : 0.0f);
        }
        #pragma unroll
        for (int i = 0; i < 8; ++i) v[i] = tmp[i];
      } else if (MODE == 2) {
        const unsigned short* src = (k0 < P_) ? (A1 + (t0 + arow) * P_ + k0)
                                              : (A2 + (t0 + arow) * P_ + (k0 - P_));
        v = *(const bf16x8*)(src + aks * 8);
      } else {
        v = *(const bf16x8*)(A1 + (t0 + arow) * P_ + k0 + aks * 8);
      }
      const int slot = aks ^ ((arow >> 1) & 3);
      *(bf16x8*)&As[arow * 32 + slot * 8] = v;
    }
    // ---- stage B tile: WT cols [256][32]
    #pragma unroll
    for (int cc = 0; cc < 2; ++cc) {
      const int c = tid + cc * 512;
      const int col = c >> 2, ks = c & 3;
      bf16x8 v = *(const bf16x8*)(WT + (long)col * K + k0 + ks * 8);
      const int slot = ks ^ ((col >> 1) & 3);
      *(bf16x8*)&Bs[col * 32 + slot * 8] = v;
    }
    __syncthreads();
    // ---- frags + MFMA
    bf16x8 af[4], bfr[4];
    #pragma unroll
    for (int fr = 0; fr < 4; ++fr) {
      const int row = wr * 64 + fr * 16 + ln;
      af[fr] = *(const bf16x8*)&As[row * 32 + ((g ^ ((row >> 1) & 3)) * 8)];
    }
    #pragma unroll
    for (int fc = 0; fc < 4; ++fc) {
      const int col = wc * 64 + fc * 16 + ln;
      bfr[fc] = *(const bf16x8*)&Bs[col * 32 + ((g ^ ((col >> 1) & 3)) * 8)];
    }
    #pragma unroll
    for (int fr = 0; fr < 4; ++fr)
      #pragma unroll
      for (int fc = 0; fc < 4; ++fc)
        acc[fr][fc] = __builtin_amdgcn_mfma_f32_16x16x32_bf16(af[fr], bfr[fc], acc[fr][fc], 0, 0, 0);
    __syncthreads();
  }

  // ---- epilogue
  const int g4 = g * 4;
  if (AGG) {
    const int b = (int)(t0 >> 8);
    const int s0 = (int)(t0 & 255);
    const int len = lens[b];
    #pragma unroll
    for (int fc = 0; fc < 4; ++fc) {
      const int col = wc * 64 + fc * 16 + ln;
      const float bb = bias[col];
      float sum = 0.0f;
      #pragma unroll
      for (int fr = 0; fr < 4; ++fr) {
        const int sbase = s0 + wr * 64 + fr * 16 + g4;
        #pragma unroll
        for (int r = 0; r < 4; ++r) {
          if (sbase + r < len) sum += fmaxf(acc[fr][fc][r] + bb, 0.0f);
        }
      }
      sum += __shfl_xor(sum, 16, 64);
      sum += __shfl_xor(sum, 32, 64);
      if (g == 0) atomicAdd(&aggOut[(long)b * P_ + col], sum);
    }
  } else {
    #pragma unroll
    for (int fc = 0; fc < 4; ++fc) {
      const int col = wc * 64 + fc * 16 + ln;
      const float bb = bias ? bias[col] : 0.0f;
      #pragma unroll
      for (int fr = 0; fr < 4; ++fr) {
        const long rbase = t0 + wr * 64 + fr * 16 + g4;
        #pragma unroll
        for (int r = 0; r < 4; ++r) {
          float v = acc[fr][fc][r] + bb;
          if (RELU) v = fmaxf(v, 0.0f);
          outp[(rbase + r) * P_ + col] = (unsigned short)f2bf(v);
        }
      }
    }
  }
}

// ---------------- sim = (f1 @ f2^T) * mask, bf16 MFMA; writes sim AND simT (fp32) ----------------
__global__ __launch_bounds__(512) void sim_mfma(
    const unsigned short* __restrict__ f1, const unsigned short* __restrict__ f2,
    const int* __restrict__ len1, const int* __restrict__ len2,
    float* __restrict__ simp, float* __restrict__ simTp)
{
  __shared__ unsigned short As[128 * 32];
  __shared__ unsigned short Bs[256 * 32];
  const int tid = threadIdx.x;
  const int lane = tid & 63;
  const int w = tid >> 6;
  const int wr = w >> 2, wc = w & 3;
  const int b = blockIdx.y;
  const int i0 = blockIdx.x * 128;
  const int g = lane >> 4, ln = lane & 15;
  const unsigned short* Arows = f1 + ((long)b * S_ + i0) * P_;
  const unsigned short* Brows = f2 + (long)b * S_ * P_;

  f32x4 acc[4][4];
  #pragma unroll
  for (int i = 0; i < 4; ++i)
    #pragma unroll
    for (int j = 0; j < 4; ++j) acc[i][j] = (f32x4){0.f, 0.f, 0.f, 0.f};

  const int arow = tid >> 2, aks = tid & 3;
  for (int k0 = 0; k0 < P_; k0 += 32) {
    {
      bf16x8 v = *(const bf16x8*)(Arows + (long)arow * P_ + k0 + aks * 8);
      const int slot = aks ^ ((arow >> 1) & 3);
      *(bf16x8*)&As[arow * 32 + slot * 8] = v;
    }
    #pragma unroll
    for (int cc = 0; cc < 2; ++cc) {
      const int c = tid + cc * 512;
      const int col = c >> 2, ks = c & 3;
      bf16x8 v = *(const bf16x8*)(Brows + (long)col * P_ + k0 + ks * 8);
      const int slot = ks ^ ((col >> 1) & 3);
      *(bf16x8*)&Bs[col * 32 + slot * 8] = v;
    }
    __syncthreads();
    bf16x8 af[4], bfr[4];
    #pragma unroll
    for (int fr = 0; fr < 4; ++fr) {
      const int row = wr * 64 + fr * 16 + ln;
      af[fr] = *(const bf16x8*)&As[row * 32 + ((g ^ ((row >> 1) & 3)) * 8)];
    }
    #pragma unroll
    for (int fc = 0; fc < 4; ++fc) {
      const int col = wc * 64 + fc * 16 + ln;
      bfr[fc] = *(const bf16x8*)&Bs[col * 32 + ((g ^ ((col >> 1) & 3)) * 8)];
    }
    #pragma unroll
    for (int fr = 0; fr < 4; ++fr)
      #pragma unroll
      for (int fc = 0; fc < 4; ++fc)
        acc[fr][fc] = __builtin_amdgcn_mfma_f32_16x16x32_bf16(af[fr], bfr[fc], acc[fr][fc], 0, 0, 0);
    __syncthreads();
  }

  const int l1 = len1[b], l2 = len2[b];
  const int g4 = g * 4;
  #pragma unroll
  for (int fc = 0; fc < 4; ++fc) {
    const int j = wc * 64 + fc * 16 + ln;
    const float mj = (j < l2) ? 1.0f : 0.0f;
    #pragma unroll
    for (int fr = 0; fr < 4; ++fr) {
      const int ib = i0 + wr * 64 + fr * 16 + g4;
      float4 o;
      float* op = &o.x;
      #pragma unroll
      for (int r = 0; r < 4; ++r) {
        const float m = ((ib + r) < l1) ? mj : 0.0f;
        op[r] = acc[fr][fc][r] * m;
        simp[((long)b * S_ + ib + r) * S_ + j] = op[r];
      }
      *(float4*)&simTp[((long)b * S_ + j) * S_ + ib] = o;
    }
  }
}

// ---------------- row softmax of M + weighted sum over X (bf16) ----------------
// out[b, r, :] = softmax_j(M[b, r, :]) @ X[b, :, :]
__global__ __launch_bounds__(256) void attend_kernel(
    const float* __restrict__ M, const unsigned short* __restrict__ X,
    unsigned short* __restrict__ outp)
{
  __shared__ float ps[8][S_];
  const int b = blockIdx.x;
  const int r0 = blockIdx.y * 8;
  const int tid = threadIdx.x;
  const float* Mb = M + (long)b * S_ * S_;
  {
    const int r = tid >> 5, l = tid & 31;
    const int rr = r0 + r;
    float v[8];
    #pragma unroll
    for (int k = 0; k < 8; ++k) v[k] = Mb[(long)rr * S_ + l + 32 * k];
    float m = v[0];
    #pragma unroll
    for (int k = 1; k < 8; ++k) m = fmaxf(m, v[k]);
    #pragma unroll
    for (int d = 16; d >= 1; d >>= 1) m = fmaxf(m, __shfl_xor(m, d, 32));
    float sum = 0.0f;
    #pragma unroll
    for (int k = 0; k < 8; ++k) { v[k] = expf(v[k] - m); sum += v[k]; }
    #pragma unroll
    for (int d = 16; d >= 1; d >>= 1) sum += __shfl_xor(sum, d, 32);
    const float inv = 1.0f / sum;
    #pragma unroll
    for (int k = 0; k < 8; ++k) ps[r][l + 32 * k] = v[k] * inv;
  }
  __syncthreads();
  float acc[8] = {0,0,0,0,0,0,0,0};
  const unsigned short* Xb = X + (long)b * S_ * P_;
  for (int j = 0; j < S_; j += 4) {
    const float x0 = bf2f(Xb[(long)(j + 0) * P_ + tid]);
    const float x1 = bf2f(Xb[(long)(j + 1) * P_ + tid]);
    const float x2 = bf2f(Xb[(long)(j + 2) * P_ + tid]);
    const float x3 = bf2f(Xb[(long)(j + 3) * P_ + tid]);
    #pragma unroll
    for (int r = 0; r < 8; ++r) {
      const float4 p4 = *(const float4*)&ps[r][j];
      acc[r] += p4.x * x0 + p4.y * x1 + p4.z * x2 + p4.w * x3;
    }
  }
  #pragma unroll
  for (int r = 0; r < 8; ++r)
    outp[((long)b * S_ + r0 + r) * P_ + tid] = (unsigned short)f2bf(acc[r]);
}

// ---------------- final head (fp32) ----------------
__global__ __launch_bounds__(256) void head_kernel(
    const float* __restrict__ v1s, const float* __restrict__ v2s,
    const float* __restrict__ HW1p, const float* __restrict__ Hb1p,
    const float* __restrict__ HW2p, const float* __restrict__ Hb2p,
    const float* __restrict__ Wout, const float* __restrict__ bout,
    float* __restrict__ y)
{
  __shared__ float xin[2 * P_];
  __shared__ float h[P_];
  const int b = blockIdx.x;
  const int tid = threadIdx.x;
  xin[tid] = v1s[(long)b * P_ + tid];
  xin[P_ + tid] = v2s[(long)b * P_ + tid];
  __syncthreads();
  float acc = Hb1p[tid];
  for (int e = 0; e < 2 * P_; ++e) acc += xin[e] * HW1p[(long)e * P_ + tid];
  h[tid] = fmaxf(acc, 0.0f);
  __syncthreads();
  float acc2 = Hb2p[tid];
  for (int e = 0; e < P_; ++e) acc2 += h[e] * HW2p[(long)e * P_ + tid];
  const float h2 = fmaxf(acc2, 0.0f);
  __syncthreads();
  xin[tid] = h2;
  __syncthreads();
  if (tid < C_) {
    float a = bout[tid];
    for (int d = 0; d < D_; ++d) a += xin[d] * Wout[d * C_ + tid];
    y[(long)b * C_ + tid] = a;
  }
}

// ---------------- launch ----------------
extern "C" void kernel_launch(void* const* d_in, const int* in_sizes, int n_in,
                              void* d_out, int out_size, void* d_ws, size_t ws_size,
                              hipStream_t stream)
{
  const int*   x1    = (const int*)d_in[0];
  const int*   x2    = (const int*)d_in[1];
  const int*   len1  = (const int*)d_in[2];
  const int*   len2  = (const int*)d_in[3];
  const float* emb   = (const float*)d_in[4];
  const float* Wproj = (const float*)d_in[5];
  const float* FW1   = (const float*)d_in[6];
  const float* Fb1   = (const float*)d_in[7];
  const float* FW2   = (const float*)d_in[8];
  const float* Fb2   = (const float*)d_in[9];
  const float* GW1   = (const float*)d_in[10];
  const float* Gb1   = (const float*)d_in[11];
  const float* GW2   = (const float*)d_in[12];
  const float* Gb2   = (const float*)d_in[13];
  const float* HW1   = (const float*)d_in[14];
  const float* Hb1   = (const float*)d_in[15];
  const float* HW2   = (const float*)d_in[16];
  const float* Hb2   = (const float*)d_in[17];
  const float* Wout  = (const float*)d_in[18];
  const float* bout  = (const float*)d_in[19];
  float* out = (float*)d_out;

  float* ws = (float*)d_ws;
  size_t o = 0;
  auto alloc = [&](size_t n) { float* p = ws + o; o += n; return p; };
  float* simb  = alloc((size_t)B_ * S_ * S_);
  float* simT  = alloc((size_t)B_ * S_ * S_);
  float* v1s   = alloc((size_t)B_ * P_);
  float* v2s   = alloc((size_t)B_ * P_);
  float* invn1 = alloc(TOK_);
  float* invn2 = alloc(TOK_);
  float* HW1p  = alloc((size_t)2 * P_ * P_); float* Hb1p = alloc(P_);
  float* HW2p  = alloc((size_t)P_ * P_);     float* Hb2p = alloc(P_);
  float* Fb1p  = alloc(P_); float* Fb2p = alloc(P_);
  float* Gb1p  = alloc(P_); float* Gb2p = alloc(P_);
  unsigned short* us = (unsigned short*)(ws + o);
  size_t uo = 0;
  auto ualloc = [&](size_t n) { unsigned short* p = us + uo; uo += n; return p; };
  unsigned short* x1pb = ualloc((size_t)TOK_ * P_);
  unsigned short* x2pb = ualloc((size_t)TOK_ * P_);
  unsigned short* hidb = ualloc((size_t)TOK_ * P_);
  unsigned short* f1b  = ualloc((size_t)TOK_ * P_);   // reused as beta
  unsigned short* f2b  = ualloc((size_t)TOK_ * P_);   // reused as alpha
  unsigned short* WpT  = ualloc((size_t)P_ * 320);
  unsigned short* FW1T = ualloc((size_t)P_ * P_);
  unsigned short* FW2T = ualloc((size_t)P_ * P_);
  unsigned short* GW1T = ualloc((size_t)P_ * 2 * P_);
  unsigned short* GW2T = ualloc((size_t)P_ * P_);
  if (o * sizeof(float) + uo * sizeof(unsigned short) > ws_size) return;

  auto g = [](int n) { return (n + 255) / 256; };

  // --- weight prep ---
  padT_bf16<<<g(P_ * 320), 256, 0, stream>>>(Wproj, WpT, E_, D_, 320, P_);
  padT_bf16<<<g(P_ * P_), 256, 0, stream>>>(FW1, FW1T, D_, D_, P_, P_);
  padT_bf16<<<g(P_ * P_), 256, 0, stream>>>(FW2, FW2T, D_, D_, P_, P_);
  padT_bf16<<<g(P_ * P_), 256, 0, stream>>>(GW2, GW2T, D_, D_, P_, P_);
  padcatT_bf16<<<g(P_ * 2 * P_), 256, 0, stream>>>(GW1, GW1T);
  padcat_kernel<<<g(2 * P_ * P_), 256, 0, stream>>>(HW1, HW1p);
  pad2d_kernel<<<g(P_ * P_), 256, 0, stream>>>(HW2, HW2p, D_, D_, P_, P_);
  pad2d_kernel<<<1, 256, 0, stream>>>(Fb1, Fb1p, 1, D_, 1, P_);
  pad2d_kernel<<<1, 256, 0, stream>>>(Fb2, Fb2p, 1, D_, 1, P_);
  pad2d_kernel<<<1, 256, 0, stream>>>(Gb1, Gb1p, 1, D_, 1, P_);
  pad2d_kernel<<<1, 256, 0, stream>>>(Gb2, Gb2p, 1, D_, 1, P_);
  pad2d_kernel<<<1, 256, 0, stream>>>(Hb1, Hb1p, 1, D_, 1, P_);
  pad2d_kernel<<<1, 256, 0, stream>>>(Hb2, Hb2p, 1, D_, 1, P_);
  zero_kernel<<<g(2 * B_ * P_), 256, 0, stream>>>(v1s, 2 * B_ * P_);

  // --- embedding norms + projection (gather GEMM, K=320) ---
  invnorm_kernel<<<TOK_ / 4, 256, 0, stream>>>(x1, emb, invn1);
  invnorm_kernel<<<TOK_ / 4, 256, 0, stream>>>(x2, emb, invn2);
  gemm_mfma<1, false, false><<<TOK_ / 128, 512, 0, stream>>>(
      nullptr, nullptr, x1, emb, invn1, WpT, nullptr, x1pb, nullptr, nullptr, 320);
  gemm_mfma<1, false, false><<<TOK_ / 128, 512, 0, stream>>>(
      nullptr, nullptr, x2, emb, invn2, WpT, nullptr, x2pb, nullptr, nullptr, 320);

  // --- F MLP ---
  gemm_mfma<0, true, false><<<TOK_ / 128, 512, 0, stream>>>(
      x1pb, nullptr, nullptr, nullptr, nullptr, FW1T, Fb1p, hidb, nullptr, nullptr, P_);
  gemm_mfma<0, true, false><<<TOK_ / 128, 512, 0, stream>>>(
      hidb, nullptr, nullptr, nullptr, nullptr, FW2T, Fb2p, f1b, nullptr, nullptr, P_);
  gemm_mfma<0, true, false><<<TOK_ / 128, 512, 0, stream>>>(
      x2pb, nullptr, nullptr, nullptr, nullptr, FW1T, Fb1p, hidb, nullptr, nullptr, P_);
  gemm_mfma<0, true, false><<<TOK_ / 128, 512, 0, stream>>>(
      hidb, nullptr, nullptr, nullptr, nullptr, FW2T, Fb2p, f2b, nullptr, nullptr, P_);

  // --- similarity (+mask), writes sim and simT ---
  {
    dim3 grid(S_ / 128, B_);
    sim_mfma<<<grid, 512, 0, stream>>>(f1b, f2b, len1, len2, simb, simT);
  }

  // --- softmax-weighted sums: beta (rows of sim), alpha (rows of simT) ---
  {
    dim3 grid(B_, S_ / 8);
    attend_kernel<<<grid, 256, 0, stream>>>(simb, x2pb, f1b);  // beta  -> f1b
    attend_kernel<<<grid, 256, 0, stream>>>(simT, x1pb, f2b);  // alpha -> f2b
  }

  // --- G MLP + masked aggregation ---
  gemm_mfma<2, true, false><<<TOK_ / 128, 512, 0, stream>>>(
      x1pb, f1b, nullptr, nullptr, nullptr, GW1T, Gb1p, hidb, nullptr, nullptr, 2 * P_);
  gemm_mfma<0, true, true><<<TOK_ / 128, 512, 0, stream>>>(
      hidb, nullptr, nullptr, nullptr, nullptr, GW2T, Gb2p, nullptr, v1s, len1, P_);
  gemm_mfma<2, true, false><<<TOK_ / 128, 512, 0, stream>>>(
      x2pb, f2b, nullptr, nullptr, nullptr, GW1T, Gb1p, hidb, nullptr, nullptr, 2 * P_);
  gemm_mfma<0, true, true><<<TOK_ / 128, 512, 0, stream>>>(
      hidb, nullptr, nullptr, nullptr, nullptr, GW2T, Gb2p, nullptr, v2s, len2, P_);

  // --- head ---
  head_kernel<<<B_, 256, 0, stream>>>(v1s, v2s, HW1p, Hb1p, HW2p, Hb2p, Wout, bout, out);
}

// Round 6
// 411.668 us; speedup vs baseline: 3.0272x; 1.5100x over previous
//
#include <hip/hip_runtime.h>
#include <math.h>

#define B_ 128
#define S_ 256
#define V_ 50000
#define E_ 300
#define D_ 200
#define C_ 3
#define P_ 256            // padded D
#define TOK_ (B_*S_)      // 32768

typedef __attribute__((ext_vector_type(8))) short bf16x8;
typedef __attribute__((ext_vector_type(4))) float f32x4;

static __device__ __forceinline__ short f2bf(float f) {
  unsigned u = __builtin_bit_cast(unsigned, f);
  u += 0x7fffu + ((u >> 16) & 1u);   // RNE
  return (short)(u >> 16);
}
static __device__ __forceinline__ float bf2f(unsigned short u) {
  unsigned v = ((unsigned)u) << 16;
  return __builtin_bit_cast(float, v);
}

// ---------------- pad / concat / zero helpers ----------------
__global__ void pad2d_kernel(const float* __restrict__ src, float* __restrict__ dst,
                             int sR, int sC, int dR, int dC) {
  int idx = blockIdx.x * 256 + threadIdx.x;
  if (idx >= dR * dC) return;
  int r = idx / dC, c = idx - r * dC;
  dst[idx] = (r < sR && c < sC) ? src[r * sC + c] : 0.0f;
}

// src [400][200] -> dst [512][256] fp32 (for HW1)
__global__ void padcat_kernel(const float* __restrict__ src, float* __restrict__ dst) {
  int idx = blockIdx.x * 256 + threadIdx.x;
  if (idx >= 512 * 256) return;
  int r = idx >> 8, c = idx & 255;
  int sr = (r < 200) ? r : ((r >= 256 && r < 456) ? (r - 56) : -1);
  dst[idx] = (sr >= 0 && c < 200) ? src[sr * 200 + c] : 0.0f;
}

// transpose-pad to bf16: dst[n][k] = src[k][n], dst [dN][dK]
__global__ void padT_bf16(const float* __restrict__ src, unsigned short* __restrict__ dst,
                          int sK, int sN, int dK, int dN) {
  int idx = blockIdx.x * 256 + threadIdx.x;
  if (idx >= dN * dK) return;
  int n = idx / dK, k = idx - n * dK;
  float v = (k < sK && n < sN) ? src[k * sN + n] : 0.0f;
  dst[idx] = (unsigned short)f2bf(v);
}

// GW1 [400][200] -> GW1T bf16 [256][512]
__global__ void padcatT_bf16(const float* __restrict__ src, unsigned short* __restrict__ dst) {
  int idx = blockIdx.x * 256 + threadIdx.x;
  if (idx >= 256 * 512) return;
  int n = idx >> 9, k = idx & 511;
  int sk = (k < 256) ? ((k < 200) ? k : -1) : (((k - 256) < 200) ? (200 + k - 256) : -1);
  float v = (sk >= 0 && n < 200) ? src[sk * 200 + n] : 0.0f;
  dst[idx] = (unsigned short)f2bf(v);
}

__global__ void zero_kernel(float* __restrict__ p, int n) {
  int idx = blockIdx.x * 256 + threadIdx.x;
  if (idx < n) p[idx] = 0.0f;
}

__global__ void concat_ids_kernel(const int* __restrict__ a, const int* __restrict__ b,
                                  int* __restrict__ dst) {
  int i = blockIdx.x * 256 + threadIdx.x;
  if (i < TOK_) dst[i] = a[i];
  else if (i < 2 * TOK_) dst[i] = b[i - TOK_];
}

__global__ void concat_lens_kernel(const int* __restrict__ a, const int* __restrict__ b,
                                   int* __restrict__ dst) {
  int i = threadIdx.x;
  if (i < B_) dst[i] = a[i];
  else dst[i] = b[i - B_];
}

// ---------------- per-token inverse embedding norm (2*TOK tokens) ----------------
__global__ __launch_bounds__(256) void invnorm_kernel(const int* __restrict__ ids,
    const float* __restrict__ emb, float* __restrict__ invn) {
  int tok = blockIdx.x * 4 + (threadIdx.x >> 6);
  int l = threadIdx.x & 63;
  long base = (long)ids[tok] * E_;
  float ss = 0.0f;
  for (int e = l; e < E_; e += 64) { float v = emb[base + e]; ss += v * v; }
  #pragma unroll
  for (int d = 32; d >= 1; d >>= 1) ss += __shfl_xor(ss, d, 64);
  if (l == 0) invn[tok] = 1.0f / sqrtf(ss);
}

// ---------------- batch transpose bf16: out[b][d][s] = in[b][s][d], 256x256 per batch ----------------
__global__ __launch_bounds__(256) void transpose_bf16(
    const unsigned short* __restrict__ in, unsigned short* __restrict__ outp) {
  __shared__ unsigned short t[64][66];
  const int b = blockIdx.x;
  const int r0 = blockIdx.y * 64, c0 = blockIdx.z * 64;
  const unsigned short* src = in + (long)b * S_ * P_;
  unsigned short* dst = outp + (long)b * P_ * S_;
  const int tx = threadIdx.x & 63, ty = threadIdx.x >> 6;
  #pragma unroll
  for (int i = 0; i < 16; ++i)
    t[ty * 16 + i][tx] = src[(long)(r0 + ty * 16 + i) * P_ + c0 + tx];
  __syncthreads();
  #pragma unroll
  for (int i = 0; i < 16; ++i)
    dst[(long)(c0 + ty * 16 + i) * S_ + r0 + tx] = t[tx][ty * 16 + i];
}

// ---------------- bf16 MFMA GEMM: out[M x 256] = act(A @ W + b) ----------------
// Tile: 128 rows x 256 cols, 512 threads (8 waves, 2x4), BK=32.
// MODE 0: A = A1 bf16 [M][256]
// MODE 1: A row t = bf16(emb[ids[t]] * invn[t])  (K=320 padded, valid k<300)
// MODE 2: A = concat(A1 [M][256], A2 [M][256]) bf16  (K=512)
// WT: bf16 [256][K]  (W transposed)
// AGG: masked (lens[b], b=row/256) sum of relu rows -> atomicAdd into aggOut[.][256] fp32
template<int MODE, bool RELU, bool AGG>
__global__ __launch_bounds__(512) void gemm_mfma(
    const unsigned short* __restrict__ A1, const unsigned short* __restrict__ A2,
    const int* __restrict__ ids, const float* __restrict__ emb,
    const float* __restrict__ invn,
    const unsigned short* __restrict__ WT, const float* __restrict__ bias,
    unsigned short* __restrict__ outp, float* __restrict__ aggOut,
    const int* __restrict__ lens, int K)
{
  __shared__ unsigned short As[128 * 32];   // swizzled: 16B slot = kslot ^ ((row>>1)&3)
  __shared__ unsigned short Bs[256 * 32];
  const int tid = threadIdx.x;
  const int lane = tid & 63;
  const int w = tid >> 6;
  const int wr = w >> 2, wc = w & 3;
  const long t0 = (long)blockIdx.x * 128;
  const int g = lane >> 4, ln = lane & 15;

  f32x4 acc[4][4];
  #pragma unroll
  for (int i = 0; i < 4; ++i)
    #pragma unroll
    for (int j = 0; j < 4; ++j) acc[i][j] = (f32x4){0.f, 0.f, 0.f, 0.f};

  const int arow = tid >> 2, aks = tid & 3;

  for (int k0 = 0; k0 < K; k0 += 32) {
    { // stage A tile [128][32]
      bf16x8 v;
      if (MODE == 1) {
        const long t = t0 + arow;
        const long base = (long)ids[t] * E_;
        const float inv = invn[t];
        const int kb = k0 + aks * 8;
        short tmp[8];
        #pragma unroll
        for (int i = 0; i < 8; ++i) {
          const int k = kb + i;
          tmp[i] = f2bf((k < E_) ? emb[base + k] * inv : 0.0f);
        }
        #pragma unroll
        for (int i = 0; i < 8; ++i) v[i] = tmp[i];
      } else if (MODE == 2) {
        const unsigned short* src = (k0 < P_) ? (A1 + (t0 + arow) * P_ + k0)
                                              : (A2 + (t0 + arow) * P_ + (k0 - P_));
        v = *(const bf16x8*)(src + aks * 8);
      } else {
        v = *(const bf16x8*)(A1 + (t0 + arow) * P_ + k0 + aks * 8);
      }
      const int slot = aks ^ ((arow >> 1) & 3);
      *(bf16x8*)&As[arow * 32 + slot * 8] = v;
    }
    // stage B tile: WT cols [256][32]
    #pragma unroll
    for (int cc = 0; cc < 2; ++cc) {
      const int c = tid + cc * 512;
      const int col = c >> 2, ks = c & 3;
      bf16x8 v = *(const bf16x8*)(WT + (long)col * K + k0 + ks * 8);
      const int slot = ks ^ ((col >> 1) & 3);
      *(bf16x8*)&Bs[col * 32 + slot * 8] = v;
    }
    __syncthreads();
    bf16x8 af[4], bfr[4];
    #pragma unroll
    for (int fr = 0; fr < 4; ++fr) {
      const int row = wr * 64 + fr * 16 + ln;
      af[fr] = *(const bf16x8*)&As[row * 32 + ((g ^ ((row >> 1) & 3)) * 8)];
    }
    #pragma unroll
    for (int fc = 0; fc < 4; ++fc) {
      const int col = wc * 64 + fc * 16 + ln;
      bfr[fc] = *(const bf16x8*)&Bs[col * 32 + ((g ^ ((col >> 1) & 3)) * 8)];
    }
    #pragma unroll
    for (int fr = 0; fr < 4; ++fr)
      #pragma unroll
      for (int fc = 0; fc < 4; ++fc)
        acc[fr][fc] = __builtin_amdgcn_mfma_f32_16x16x32_bf16(af[fr], bfr[fc], acc[fr][fc], 0, 0, 0);
    __syncthreads();
  }

  const int g4 = g * 4;
  if (AGG) {
    const int b = (int)(t0 >> 8);
    const int s0 = (int)(t0 & 255);
    const int len = lens[b];
    #pragma unroll
    for (int fc = 0; fc < 4; ++fc) {
      const int col = wc * 64 + fc * 16 + ln;
      const float bb = bias[col];
      float sum = 0.0f;
      #pragma unroll
      for (int fr = 0; fr < 4; ++fr) {
        const int sbase = s0 + wr * 64 + fr * 16 + g4;
        #pragma unroll
        for (int r = 0; r < 4; ++r) {
          if (sbase + r < len) sum += fmaxf(acc[fr][fc][r] + bb, 0.0f);
        }
      }
      sum += __shfl_xor(sum, 16, 64);
      sum += __shfl_xor(sum, 32, 64);
      if (g == 0) atomicAdd(&aggOut[(long)b * P_ + col], sum);
    }
  } else {
    #pragma unroll
    for (int fc = 0; fc < 4; ++fc) {
      const int col = wc * 64 + fc * 16 + ln;
      const float bb = bias ? bias[col] : 0.0f;
      #pragma unroll
      for (int fr = 0; fr < 4; ++fr) {
        const long rbase = t0 + wr * 64 + fr * 16 + g4;
        #pragma unroll
        for (int r = 0; r < 4; ++r) {
          float v = acc[fr][fc][r] + bb;
          if (RELU) v = fmaxf(v, 0.0f);
          outp[(rbase + r) * P_ + col] = (unsigned short)f2bf(v);
        }
      }
    }
  }
}

// ---------------- fused attention: out = softmax(mask(Afeat @ Bfeat^T)) @ X ----------------
// blockIdx.z selects direction: z=0 beta (rows=f1, cols=f2, X=x2p), z=1 alpha (swapped).
// Per block: 128 rows (i0 tile) of batch b. Phase 1: S = A@B^T (K=256 features).
// Softmax over all 256 cols (in-register + LDS cross-wave reduce). Phase 2: P@X via
// MFMA with P staged bf16 in LDS (swizzled) and X read from XT [.][P][S].
__global__ __launch_bounds__(512) void attend_fused(
    const unsigned short* __restrict__ f12, const unsigned short* __restrict__ x12T,
    const int* __restrict__ lens12, unsigned short* __restrict__ out12)
{
  __shared__ unsigned short As[128 * 32];
  __shared__ unsigned short Bs[256 * 32];
  __shared__ unsigned short Pt[128 * 256];
  __shared__ float redmax[128][4];
  __shared__ float redsum[128][4];

  const int tid = threadIdx.x;
  const int lane = tid & 63;
  const int w = tid >> 6;
  const int wr = w >> 2, wc = w & 3;
  const int b = blockIdx.y;
  const int z = blockIdx.z;
  const int i0 = blockIdx.x * 128;
  const int g = lane >> 4, ln = lane & 15;

  const unsigned short* Afeat = f12 + (size_t)z * TOK_ * P_;
  const unsigned short* Bfeat = f12 + (size_t)(1 - z) * TOK_ * P_;
  const unsigned short* XT    = x12T + (size_t)(1 - z) * TOK_ * P_;
  unsigned short* outp        = out12 + (size_t)z * TOK_ * P_;
  const int l1 = lens12[z * B_ + b];        // row mask len
  const int l2 = lens12[(1 - z) * B_ + b];  // col mask len

  const unsigned short* Arows = Afeat + ((long)b * S_ + i0) * P_;
  const unsigned short* Brows = Bfeat + (long)b * S_ * P_;

  f32x4 acc[4][4];
  #pragma unroll
  for (int i = 0; i < 4; ++i)
    #pragma unroll
    for (int j = 0; j < 4; ++j) acc[i][j] = (f32x4){0.f, 0.f, 0.f, 0.f};

  const int arow = tid >> 2, aks = tid & 3;
  // ---- phase 1: S = A @ B^T over features ----
  for (int k0 = 0; k0 < P_; k0 += 32) {
    {
      bf16x8 v = *(const bf16x8*)(Arows + (long)arow * P_ + k0 + aks * 8);
      const int slot = aks ^ ((arow >> 1) & 3);
      *(bf16x8*)&As[arow * 32 + slot * 8] = v;
    }
    #pragma unroll
    for (int cc = 0; cc < 2; ++cc) {
      const int c = tid + cc * 512;
      const int col = c >> 2, ks = c & 3;
      bf16x8 v = *(const bf16x8*)(Brows + (long)col * P_ + k0 + ks * 8);
      const int slot = ks ^ ((col >> 1) & 3);
      *(bf16x8*)&Bs[col * 32 + slot * 8] = v;
    }
    __syncthreads();
    bf16x8 af[4], bfr[4];
    #pragma unroll
    for (int fr = 0; fr < 4; ++fr) {
      const int row = wr * 64 + fr * 16 + ln;
      af[fr] = *(const bf16x8*)&As[row * 32 + ((g ^ ((row >> 1) & 3)) * 8)];
    }
    #pragma unroll
    for (int fc = 0; fc < 4; ++fc) {
      const int col = wc * 64 + fc * 16 + ln;
      bfr[fc] = *(const bf16x8*)&Bs[col * 32 + ((g ^ ((col >> 1) & 3)) * 8)];
    }
    #pragma unroll
    for (int fr = 0; fr < 4; ++fr)
      #pragma unroll
      for (int fc = 0; fc < 4; ++fc)
        acc[fr][fc] = __builtin_amdgcn_mfma_f32_16x16x32_bf16(af[fr], bfr[fc], acc[fr][fc], 0, 0, 0);
    __syncthreads();
  }

  // ---- mask + row softmax (rows spread over 4 wc waves: LDS reduce) ----
  const int g4 = g * 4;
  // mask in-register (exp(0) participates for masked entries, per reference)
  #pragma unroll
  for (int fr = 0; fr < 4; ++fr) {
    #pragma unroll
    for (int fc = 0; fc < 4; ++fc) {
      const int col = wc * 64 + fc * 16 + ln;
      const float mj = (col < l2) ? 1.0f : 0.0f;
      #pragma unroll
      for (int r = 0; r < 4; ++r) {
        const int rowg = i0 + wr * 64 + fr * 16 + g4 + r;
        acc[fr][fc][r] *= (rowg < l1) ? mj : 0.0f;
      }
    }
  }
  // per-(fr,r) partial max over this wave's 64 cols
  #pragma unroll
  for (int fr = 0; fr < 4; ++fr) {
    #pragma unroll
    for (int r = 0; r < 4; ++r) {
      float m = fmaxf(fmaxf(acc[fr][0][r], acc[fr][1][r]),
                      fmaxf(acc[fr][2][r], acc[fr][3][r]));
      m = fmaxf(m, __shfl_xor(m, 1, 64));
      m = fmaxf(m, __shfl_xor(m, 2, 64));
      m = fmaxf(m, __shfl_xor(m, 4, 64));
      m = fmaxf(m, __shfl_xor(m, 8, 64));
      if (ln == 0) redmax[wr * 64 + fr * 16 + g4 + r][wc] = m;
    }
  }
  __syncthreads();
  #pragma unroll
  for (int fr = 0; fr < 4; ++fr) {
    #pragma unroll
    for (int r = 0; r < 4; ++r) {
      const int lr = wr * 64 + fr * 16 + g4 + r;
      const float4 m4 = *(const float4*)redmax[lr];
      const float m = fmaxf(fmaxf(m4.x, m4.y), fmaxf(m4.z, m4.w));
      float s = 0.0f;
      #pragma unroll
      for (int fc = 0; fc < 4; ++fc) {
        const float e = __expf(acc[fr][fc][r] - m);
        acc[fr][fc][r] = e;
        s += e;
      }
      s += __shfl_xor(s, 1, 64);
      s += __shfl_xor(s, 2, 64);
      s += __shfl_xor(s, 4, 64);
      s += __shfl_xor(s, 8, 64);
      if (ln == 0) redsum[lr][wc] = s;
    }
  }
  __syncthreads();
  // normalize + write P tile (bf16, A-tile swizzle: 8-elem slot within 32-col chunk XOR (row>>1)&3)
  #pragma unroll
  for (int fr = 0; fr < 4; ++fr) {
    #pragma unroll
    for (int r = 0; r < 4; ++r) {
      const int lr = wr * 64 + fr * 16 + g4 + r;
      const float4 s4 = *(const float4*)redsum[lr];
      const float inv = 1.0f / (s4.x + s4.y + s4.z + s4.w);
      #pragma unroll
      for (int fc = 0; fc < 4; ++fc) {
        const int col = wc * 64 + fc * 16 + ln;
        Pt[lr * 256 + ((col & ~31) | ((((col >> 3) & 3) ^ ((lr >> 1) & 3)) << 3) | (col & 7))] =
            (unsigned short)f2bf(acc[fr][fc][r] * inv);
      }
    }
  }

  // ---- phase 2: out = P @ X (K = 256 over j), B-operand from XT ----
  f32x4 acc2[4][4];
  #pragma unroll
  for (int i = 0; i < 4; ++i)
    #pragma unroll
    for (int j = 0; j < 4; ++j) acc2[i][j] = (f32x4){0.f, 0.f, 0.f, 0.f};
  const unsigned short* XTb = XT + (long)b * P_ * S_;
  for (int k0 = 0; k0 < S_; k0 += 32) {
    #pragma unroll
    for (int cc = 0; cc < 2; ++cc) {
      const int c = tid + cc * 512;
      const int col = c >> 2, ks = c & 3;
      bf16x8 v = *(const bf16x8*)(XTb + (long)col * S_ + k0 + ks * 8);
      const int slot = ks ^ ((col >> 1) & 3);
      *(bf16x8*)&Bs[col * 32 + slot * 8] = v;
    }
    __syncthreads();   // first iteration also covers Pt writes
    bf16x8 af[4], bfr[4];
    #pragma unroll
    for (int fr = 0; fr < 4; ++fr) {
      const int row = wr * 64 + fr * 16 + ln;
      af[fr] = *(const bf16x8*)&Pt[row * 256 + k0 + ((g ^ ((row >> 1) & 3)) * 8)];
    }
    #pragma unroll
    for (int fc = 0; fc < 4; ++fc) {
      const int col = wc * 64 + fc * 16 + ln;
      bfr[fc] = *(const bf16x8*)&Bs[col * 32 + ((g ^ ((col >> 1) & 3)) * 8)];
    }
    #pragma unroll
    for (int fr = 0; fr < 4; ++fr)
      #pragma unroll
      for (int fc = 0; fc < 4; ++fc)
        acc2[fr][fc] = __builtin_amdgcn_mfma_f32_16x16x32_bf16(af[fr], bfr[fc], acc2[fr][fc], 0, 0, 0);
    __syncthreads();
  }

  #pragma unroll
  for (int fc = 0; fc < 4; ++fc) {
    const int col = wc * 64 + fc * 16 + ln;
    #pragma unroll
    for (int fr = 0; fr < 4; ++fr) {
      const long rbase = (long)b * S_ + i0 + wr * 64 + fr * 16 + g4;
      #pragma unroll
      for (int r = 0; r < 4; ++r)
        outp[(rbase + r) * P_ + col] = (unsigned short)f2bf(acc2[fr][fc][r]);
    }
  }
}

// ---------------- final head (fp32) ----------------
__global__ __launch_bounds__(256) void head_kernel(
    const float* __restrict__ v1s, const float* __restrict__ v2s,
    const float* __restrict__ HW1p, const float* __restrict__ Hb1p,
    const float* __restrict__ HW2p, const float* __restrict__ Hb2p,
    const float* __restrict__ Wout, const float* __restrict__ bout,
    float* __restrict__ y)
{
  __shared__ float xin[2 * P_];
  __shared__ float h[P_];
  const int b = blockIdx.x;
  const int tid = threadIdx.x;
  xin[tid] = v1s[(long)b * P_ + tid];
  xin[P_ + tid] = v2s[(long)b * P_ + tid];
  __syncthreads();
  float acc = Hb1p[tid];
  for (int e = 0; e < 2 * P_; ++e) acc += xin[e] * HW1p[(long)e * P_ + tid];
  h[tid] = fmaxf(acc, 0.0f);
  __syncthreads();
  float acc2 = Hb2p[tid];
  for (int e = 0; e < P_; ++e) acc2 += h[e] * HW2p[(long)e * P_ + tid];
  const float h2 = fmaxf(acc2, 0.0f);
  __syncthreads();
  xin[tid] = h2;
  __syncthreads();
  if (tid < C_) {
    float a = bout[tid];
    for (int d = 0; d < D_; ++d) a += xin[d] * Wout[d * C_ + tid];
    y[(long)b * C_ + tid] = a;
  }
}

// ---------------- launch ----------------
extern "C" void kernel_launch(void* const* d_in, const int* in_sizes, int n_in,
                              void* d_out, int out_size, void* d_ws, size_t ws_size,
                              hipStream_t stream)
{
  const int*   x1    = (const int*)d_in[0];
  const int*   x2    = (const int*)d_in[1];
  const int*   len1  = (const int*)d_in[2];
  const int*   len2  = (const int*)d_in[3];
  const float* emb   = (const float*)d_in[4];
  const float* Wproj = (const float*)d_in[5];
  const float* FW1   = (const float*)d_in[6];
  const float* Fb1   = (const float*)d_in[7];
  const float* FW2   = (const float*)d_in[8];
  const float* Fb2   = (const float*)d_in[9];
  const float* GW1   = (const float*)d_in[10];
  const float* Gb1   = (const float*)d_in[11];
  const float* GW2   = (const float*)d_in[12];
  const float* Gb2   = (const float*)d_in[13];
  const float* HW1   = (const float*)d_in[14];
  const float* Hb1   = (const float*)d_in[15];
  const float* HW2   = (const float*)d_in[16];
  const float* Hb2   = (const float*)d_in[17];
  const float* Wout  = (const float*)d_in[18];
  const float* bout  = (const float*)d_in[19];
  float* out = (float*)d_out;

  float* ws = (float*)d_ws;
  size_t o = 0;
  auto alloc = [&](size_t n) { float* p = ws + o; o += n; return p; };
  float* v12   = alloc((size_t)2 * B_ * P_);          // v1s || v2s
  float* invn12 = alloc((size_t)2 * TOK_);
  float* HW1p  = alloc((size_t)2 * P_ * P_); float* Hb1p = alloc(P_);
  float* HW2p  = alloc((size_t)P_ * P_);     float* Hb2p = alloc(P_);
  float* Fb1p  = alloc(P_); float* Fb2p = alloc(P_);
  float* Gb1p  = alloc(P_); float* Gb2p = alloc(P_);
  int* ids12  = (int*)alloc((size_t)2 * TOK_);
  int* lens12 = (int*)alloc(2 * B_);
  unsigned short* us = (unsigned short*)(ws + o);
  size_t uo = 0;
  auto ualloc = [&](size_t n) { unsigned short* p = us + uo; uo += n; return p; };
  unsigned short* x12b  = ualloc((size_t)2 * TOK_ * P_);  // x1p || x2p
  unsigned short* hid2b = ualloc((size_t)2 * TOK_ * P_);  // shared MLP hidden
  unsigned short* f12b  = ualloc((size_t)2 * TOK_ * P_);  // f1 || f2
  unsigned short* ba12b = ualloc((size_t)2 * TOK_ * P_);  // beta || alpha
  unsigned short* x12T  = ualloc((size_t)2 * TOK_ * P_);  // x1pT || x2pT
  unsigned short* WpT   = ualloc((size_t)P_ * 320);
  unsigned short* FW1T  = ualloc((size_t)P_ * P_);
  unsigned short* FW2T  = ualloc((size_t)P_ * P_);
  unsigned short* GW1T  = ualloc((size_t)P_ * 2 * P_);
  unsigned short* GW2T  = ualloc((size_t)P_ * P_);
  if (o * sizeof(float) + uo * sizeof(unsigned short) > ws_size) return;

  float* v1s = v12;
  float* v2s = v12 + (size_t)B_ * P_;

  auto g = [](int n) { return (n + 255) / 256; };

  // --- weight prep ---
  padT_bf16<<<g(P_ * 320), 256, 0, stream>>>(Wproj, WpT, E_, D_, 320, P_);
  padT_bf16<<<g(P_ * P_), 256, 0, stream>>>(FW1, FW1T, D_, D_, P_, P_);
  padT_bf16<<<g(P_ * P_), 256, 0, stream>>>(FW2, FW2T, D_, D_, P_, P_);
  padT_bf16<<<g(P_ * P_), 256, 0, stream>>>(GW2, GW2T, D_, D_, P_, P_);
  padcatT_bf16<<<g(P_ * 2 * P_), 256, 0, stream>>>(GW1, GW1T);
  padcat_kernel<<<g(2 * P_ * P_), 256, 0, stream>>>(HW1, HW1p);
  pad2d_kernel<<<g(P_ * P_), 256, 0, stream>>>(HW2, HW2p, D_, D_, P_, P_);
  pad2d_kernel<<<1, 256, 0, stream>>>(Fb1, Fb1p, 1, D_, 1, P_);
  pad2d_kernel<<<1, 256, 0, stream>>>(Fb2, Fb2p, 1, D_, 1, P_);
  pad2d_kernel<<<1, 256, 0, stream>>>(Gb1, Gb1p, 1, D_, 1, P_);
  pad2d_kernel<<<1, 256, 0, stream>>>(Gb2, Gb2p, 1, D_, 1, P_);
  pad2d_kernel<<<1, 256, 0, stream>>>(Hb1, Hb1p, 1, D_, 1, P_);
  pad2d_kernel<<<1, 256, 0, stream>>>(Hb2, Hb2p, 1, D_, 1, P_);
  zero_kernel<<<g(2 * B_ * P_), 256, 0, stream>>>(v12, 2 * B_ * P_);
  concat_ids_kernel<<<g(2 * TOK_), 256, 0, stream>>>(x1, x2, ids12);
  concat_lens_kernel<<<1, 256, 0, stream>>>(len1, len2, lens12);

  // --- embedding norms + merged projection (gather GEMM, 2*TOK rows, K=320) ---
  invnorm_kernel<<<2 * TOK_ / 4, 256, 0, stream>>>(ids12, emb, invn12);
  gemm_mfma<1, false, false><<<2 * TOK_ / 128, 512, 0, stream>>>(
      nullptr, nullptr, ids12, emb, invn12, WpT, nullptr, x12b, nullptr, nullptr, 320);

  // --- transposed projections (for attend PV B-operand), both sides in one launch ---
  {
    dim3 grid(2 * B_, 4, 4);
    transpose_bf16<<<grid, 256, 0, stream>>>(x12b, x12T);
  }

  // --- F MLP (merged, 2*TOK rows) ---
  gemm_mfma<0, true, false><<<2 * TOK_ / 128, 512, 0, stream>>>(
      x12b, nullptr, nullptr, nullptr, nullptr, FW1T, Fb1p, hid2b, nullptr, nullptr, P_);
  gemm_mfma<0, true, false><<<2 * TOK_ / 128, 512, 0, stream>>>(
      hid2b, nullptr, nullptr, nullptr, nullptr, FW2T, Fb2p, f12b, nullptr, nullptr, P_);

  // --- fused attention, both directions in ONE dispatch (z=0 beta, z=1 alpha) ---
  {
    dim3 grid(S_ / 128, B_, 2);
    attend_fused<<<grid, 512, 0, stream>>>(f12b, x12T, lens12, ba12b);
  }

  // --- G MLP (merged) + masked aggregation into v12 ---
  gemm_mfma<2, true, false><<<2 * TOK_ / 128, 512, 0, stream>>>(
      x12b, ba12b, nullptr, nullptr, nullptr, GW1T, Gb1p, hid2b, nullptr, nullptr, 2 * P_);
  gemm_mfma<0, true, true><<<2 * TOK_ / 128, 512, 0, stream>>>(
      hid2b, nullptr, nullptr, nullptr, nullptr, GW2T, Gb2p, nullptr, v12, lens12, P_);

  // --- head ---
  head_kernel<<<B_, 256, 0, stream>>>(v1s, v2s, HW1p, Hb1p, HW2p, Hb2p, Wout, bout, out);
}

// Round 7
// 397.593 us; speedup vs baseline: 3.1344x; 1.0354x over previous
//
#include <hip/hip_runtime.h>
#include <math.h>

#define B_ 128
#define S_ 256
#define V_ 50000
#define E_ 300
#define D_ 200
#define C_ 3
#define P_ 256            // padded D
#define TOK_ (B_*S_)      // 32768

typedef __attribute__((ext_vector_type(8))) short bf16x8;
typedef __attribute__((ext_vector_type(4))) float f32x4;

static __device__ __forceinline__ short f2bf(float f) {
  unsigned u = __builtin_bit_cast(unsigned, f);
  u += 0x7fffu + ((u >> 16) & 1u);   // RNE
  return (short)(u >> 16);
}

// ---------------- single fused prep kernel (weights, biases, ids, lens, zero) ----------------
// grid = 2887 blocks x 256:
//   [0,320)     WpT   bf16 [256][320]  = Wproj^T padded
//   [320,576)   FW1T  bf16 [256][256]
//   [576,832)   FW2T  bf16 [256][256]
//   [832,1088)  GW2T  bf16 [256][256]
//   [1088,1600) GW1T  bf16 [256][512]  (concat-transpose)
//   [1600,2112) HW1p  f32  [512][256]  (concat-pad)
//   [2112,2368) HW2p  f32  [256][256]
//   [2368,2374) biases f32 [6][256]
//   [2374,2630) v12 zero (65536)
//   [2630,2886) ids12 concat
//   [2886]      lens12 concat
__global__ __launch_bounds__(256) void prep_all(
    const float* __restrict__ Wproj, const float* __restrict__ FW1,
    const float* __restrict__ FW2, const float* __restrict__ GW1,
    const float* __restrict__ GW2, const float* __restrict__ HW1,
    const float* __restrict__ HW2,
    const float* __restrict__ Fb1, const float* __restrict__ Fb2,
    const float* __restrict__ Gb1, const float* __restrict__ Gb2,
    const float* __restrict__ Hb1, const float* __restrict__ Hb2,
    const int* __restrict__ x1, const int* __restrict__ x2,
    const int* __restrict__ len1, const int* __restrict__ len2,
    unsigned short* __restrict__ WpT, unsigned short* __restrict__ FW1T,
    unsigned short* __restrict__ FW2T, unsigned short* __restrict__ GW1T,
    unsigned short* __restrict__ GW2T, float* __restrict__ HW1p,
    float* __restrict__ HW2p, float* __restrict__ biases,
    float* __restrict__ v12, int* __restrict__ ids12, int* __restrict__ lens12)
{
  const int blk = blockIdx.x;
  const int tid = threadIdx.x;
  if (blk < 320) {
    int idx = blk * 256 + tid;
    int n = idx / 320, k = idx - n * 320;
    WpT[idx] = (unsigned short)f2bf((k < E_ && n < D_) ? Wproj[k * D_ + n] : 0.0f);
  } else if (blk < 576) {
    int idx = (blk - 320) * 256 + tid;
    int n = idx >> 8, k = idx & 255;
    FW1T[idx] = (unsigned short)f2bf((k < D_ && n < D_) ? FW1[k * D_ + n] : 0.0f);
  } else if (blk < 832) {
    int idx = (blk - 576) * 256 + tid;
    int n = idx >> 8, k = idx & 255;
    FW2T[idx] = (unsigned short)f2bf((k < D_ && n < D_) ? FW2[k * D_ + n] : 0.0f);
  } else if (blk < 1088) {
    int idx = (blk - 832) * 256 + tid;
    int n = idx >> 8, k = idx & 255;
    GW2T[idx] = (unsigned short)f2bf((k < D_ && n < D_) ? GW2[k * D_ + n] : 0.0f);
  } else if (blk < 1600) {
    int idx = (blk - 1088) * 256 + tid;
    int n = idx >> 9, k = idx & 511;
    int sk = (k < 256) ? ((k < D_) ? k : -1) : (((k - 256) < D_) ? (D_ + k - 256) : -1);
    GW1T[idx] = (unsigned short)f2bf((sk >= 0 && n < D_) ? GW1[sk * D_ + n] : 0.0f);
  } else if (blk < 2112) {
    int idx = (blk - 1600) * 256 + tid;
    int r = idx >> 8, c = idx & 255;
    int sr = (r < D_) ? r : ((r >= 256 && r < 256 + D_) ? (r - 56) : -1);
    HW1p[idx] = (sr >= 0 && c < D_) ? HW1[sr * D_ + c] : 0.0f;
  } else if (blk < 2368) {
    int idx = (blk - 2112) * 256 + tid;
    int r = idx >> 8, c = idx & 255;
    HW2p[idx] = (r < D_ && c < D_) ? HW2[r * D_ + c] : 0.0f;
  } else if (blk < 2374) {
    int j = blk - 2368;
    const float* src = (j == 0) ? Fb1 : (j == 1) ? Fb2 : (j == 2) ? Gb1
                      : (j == 3) ? Gb2 : (j == 4) ? Hb1 : Hb2;
    biases[j * 256 + tid] = (tid < D_) ? src[tid] : 0.0f;
  } else if (blk < 2630) {
    v12[(blk - 2374) * 256 + tid] = 0.0f;
  } else if (blk < 2886) {
    int idx = (blk - 2630) * 256 + tid;
    ids12[idx] = (idx < TOK_) ? x1[idx] : x2[idx - TOK_];
  } else {
    if (tid < B_) lens12[tid] = len1[tid];
    else if (tid < 2 * B_) lens12[tid] = len2[tid - B_];
  }
}

// ---------------- per-token inverse embedding norm (2*TOK tokens) ----------------
__global__ __launch_bounds__(256) void invnorm_kernel(const int* __restrict__ ids,
    const float* __restrict__ emb, float* __restrict__ invn) {
  int tok = blockIdx.x * 4 + (threadIdx.x >> 6);
  int l = threadIdx.x & 63;
  long base = (long)ids[tok] * E_;
  float ss = 0.0f;
  for (int e = l; e < E_; e += 64) { float v = emb[base + e]; ss += v * v; }
  #pragma unroll
  for (int d = 32; d >= 1; d >>= 1) ss += __shfl_xor(ss, d, 64);
  if (l == 0) invn[tok] = 1.0f / sqrtf(ss);
}

// ---------------- batch transpose bf16: out[b][d][s] = in[b][s][d] ----------------
__global__ __launch_bounds__(256) void transpose_bf16(
    const unsigned short* __restrict__ in, unsigned short* __restrict__ outp) {
  __shared__ unsigned short t[64][66];
  const int b = blockIdx.x;
  const int r0 = blockIdx.y * 64, c0 = blockIdx.z * 64;
  const unsigned short* src = in + (long)b * S_ * P_;
  unsigned short* dst = outp + (long)b * P_ * S_;
  const int tx = threadIdx.x & 63, ty = threadIdx.x >> 6;
  #pragma unroll
  for (int i = 0; i < 16; ++i)
    t[ty * 16 + i][tx] = src[(long)(r0 + ty * 16 + i) * P_ + c0 + tx];
  __syncthreads();
  #pragma unroll
  for (int i = 0; i < 16; ++i)
    dst[(long)(c0 + ty * 16 + i) * S_ + r0 + tx] = t[tx][ty * 16 + i];
}

// ---------------- projection GEMM (gather, MODE1-style): 512 threads ----------------
__global__ __launch_bounds__(512) void proj_mfma(
    const int* __restrict__ ids, const float* __restrict__ emb,
    const float* __restrict__ invn, const unsigned short* __restrict__ WT,
    unsigned short* __restrict__ outp, int K)
{
  __shared__ unsigned short As[128 * 32];
  __shared__ unsigned short Bs[256 * 32];
  const int tid = threadIdx.x;
  const int lane = tid & 63;
  const int w = tid >> 6;
  const int wr = w >> 2, wc = w & 3;
  const long t0 = (long)blockIdx.x * 128;
  const int g = lane >> 4, ln = lane & 15;

  f32x4 acc[4][4];
  #pragma unroll
  for (int i = 0; i < 4; ++i)
    #pragma unroll
    for (int j = 0; j < 4; ++j) acc[i][j] = (f32x4){0.f, 0.f, 0.f, 0.f};

  const int arow = tid >> 2, aks = tid & 3;
  for (int k0 = 0; k0 < K; k0 += 32) {
    {
      const long t = t0 + arow;
      const long base = (long)ids[t] * E_;
      const float inv = invn[t];
      const int kb = k0 + aks * 8;
      short tmp[8];
      #pragma unroll
      for (int i = 0; i < 8; ++i) {
        const int k = kb + i;
        tmp[i] = f2bf((k < E_) ? emb[base + k] * inv : 0.0f);
      }
      bf16x8 v;
      #pragma unroll
      for (int i = 0; i < 8; ++i) v[i] = tmp[i];
      const int slot = aks ^ ((arow >> 1) & 3);
      *(bf16x8*)&As[arow * 32 + slot * 8] = v;
    }
    #pragma unroll
    for (int cc = 0; cc < 2; ++cc) {
      const int c = tid + cc * 512;
      const int col = c >> 2, ks = c & 3;
      bf16x8 v = *(const bf16x8*)(WT + (long)col * K + k0 + ks * 8);
      const int slot = ks ^ ((col >> 1) & 3);
      *(bf16x8*)&Bs[col * 32 + slot * 8] = v;
    }
    __syncthreads();
    bf16x8 af[4], bfr[4];
    #pragma unroll
    for (int fr = 0; fr < 4; ++fr) {
      const int row = wr * 64 + fr * 16 + ln;
      af[fr] = *(const bf16x8*)&As[row * 32 + ((g ^ ((row >> 1) & 3)) * 8)];
    }
    #pragma unroll
    for (int fc = 0; fc < 4; ++fc) {
      const int col = wc * 64 + fc * 16 + ln;
      bfr[fc] = *(const bf16x8*)&Bs[col * 32 + ((g ^ ((col >> 1) & 3)) * 8)];
    }
    #pragma unroll
    for (int fr = 0; fr < 4; ++fr)
      #pragma unroll
      for (int fc = 0; fc < 4; ++fc)
        acc[fr][fc] = __builtin_amdgcn_mfma_f32_16x16x32_bf16(af[fr], bfr[fc], acc[fr][fc], 0, 0, 0);
    __syncthreads();
  }
  const int g4 = g * 4;
  #pragma unroll
  for (int fc = 0; fc < 4; ++fc) {
    const int col = wc * 64 + fc * 16 + ln;
    #pragma unroll
    for (int fr = 0; fr < 4; ++fr) {
      const long rbase = t0 + wr * 64 + fr * 16 + g4;
      #pragma unroll
      for (int r = 0; r < 4; ++r)
        outp[(rbase + r) * P_ + col] = (unsigned short)f2bf(acc[fr][fc][r]);
    }
  }
}

// ---------------- fused two-layer MLP: out = relu(relu(A@W1+b1)@W2+b2) ----------------
// 1024 threads (16 waves, 2x8), 128-row tile, hidden staged bf16 in LDS (swizzled).
// MODE1 0: A = A1 [M][256] (K1=256). MODE1 2: A = concat(A1,A2) (K1=512).
// AGG: masked (lens[row/256]) column-sum of relu rows -> atomicAdd aggOut[.][256].
template<int MODE1, bool AGG>
__global__ __launch_bounds__(1024) void fused_mlp(
    const unsigned short* __restrict__ A1, const unsigned short* __restrict__ A2,
    const unsigned short* __restrict__ W1T, const float* __restrict__ b1,
    const unsigned short* __restrict__ W2T, const float* __restrict__ b2,
    unsigned short* __restrict__ outp, float* __restrict__ aggOut,
    const int* __restrict__ lens, int K1)
{
  __shared__ unsigned short As[128 * 32];
  __shared__ unsigned short Bs[256 * 32];
  __shared__ unsigned short Hs[128 * 256];
  const int tid = threadIdx.x;
  const int lane = tid & 63;
  const int w = tid >> 6;               // 0..15
  const int wr = w >> 3, wc = w & 7;    // 2 x 8 waves
  const long t0 = (long)blockIdx.x * 128;
  const int g = lane >> 4, ln = lane & 15;
  const int g4 = g * 4;

  f32x4 acc[4][2];
  #pragma unroll
  for (int i = 0; i < 4; ++i)
    #pragma unroll
    for (int j = 0; j < 2; ++j) acc[i][j] = (f32x4){0.f, 0.f, 0.f, 0.f};

  // ---- stage 1: H = relu(A @ W1 + b1)
  for (int k0 = 0; k0 < K1; k0 += 32) {
    if (tid < 512) {
      const int arow = tid >> 2, aks = tid & 3;
      bf16x8 v;
      if (MODE1 == 2) {
        const unsigned short* src = (k0 < P_) ? (A1 + (t0 + arow) * P_ + k0)
                                              : (A2 + (t0 + arow) * P_ + (k0 - P_));
        v = *(const bf16x8*)(src + aks * 8);
      } else {
        v = *(const bf16x8*)(A1 + (t0 + arow) * P_ + k0 + aks * 8);
      }
      const int slot = aks ^ ((arow >> 1) & 3);
      *(bf16x8*)&As[arow * 32 + slot * 8] = v;
    }
    {
      const int col = tid >> 2, ks = tid & 3;
      bf16x8 v = *(const bf16x8*)(W1T + (long)col * K1 + k0 + ks * 8);
      const int slot = ks ^ ((col >> 1) & 3);
      *(bf16x8*)&Bs[col * 32 + slot * 8] = v;
    }
    __syncthreads();
    bf16x8 af[4], bfr[2];
    #pragma unroll
    for (int fr = 0; fr < 4; ++fr) {
      const int row = wr * 64 + fr * 16 + ln;
      af[fr] = *(const bf16x8*)&As[row * 32 + ((g ^ ((row >> 1) & 3)) * 8)];
    }
    #pragma unroll
    for (int fc = 0; fc < 2; ++fc) {
      const int col = wc * 32 + fc * 16 + ln;
      bfr[fc] = *(const bf16x8*)&Bs[col * 32 + ((g ^ ((col >> 1) & 3)) * 8)];
    }
    #pragma unroll
    for (int fr = 0; fr < 4; ++fr)
      #pragma unroll
      for (int fc = 0; fc < 2; ++fc)
        acc[fr][fc] = __builtin_amdgcn_mfma_f32_16x16x32_bf16(af[fr], bfr[fc], acc[fr][fc], 0, 0, 0);
    __syncthreads();
  }

  // write H to LDS (bf16, A-tile swizzle)
  #pragma unroll
  for (int fc = 0; fc < 2; ++fc) {
    const int col = wc * 32 + fc * 16 + ln;
    const float bb = b1[col];
    #pragma unroll
    for (int fr = 0; fr < 4; ++fr) {
      #pragma unroll
      for (int r = 0; r < 4; ++r) {
        const int lr = wr * 64 + fr * 16 + g4 + r;
        const float v = fmaxf(acc[fr][fc][r] + bb, 0.0f);
        Hs[lr * 256 + ((col & ~31) | ((((col >> 3) & 3) ^ ((lr >> 1) & 3)) << 3) | (col & 7))] =
            (unsigned short)f2bf(v);
      }
    }
  }

  // ---- stage 2: O = relu(H @ W2 + b2)
  f32x4 acc2[4][2];
  #pragma unroll
  for (int i = 0; i < 4; ++i)
    #pragma unroll
    for (int j = 0; j < 2; ++j) acc2[i][j] = (f32x4){0.f, 0.f, 0.f, 0.f};

  for (int k0 = 0; k0 < 256; k0 += 32) {
    {
      const int col = tid >> 2, ks = tid & 3;
      bf16x8 v = *(const bf16x8*)(W2T + (long)col * 256 + k0 + ks * 8);
      const int slot = ks ^ ((col >> 1) & 3);
      *(bf16x8*)&Bs[col * 32 + slot * 8] = v;
    }
    __syncthreads();   // covers H writes on first iteration
    bf16x8 af[4], bfr[2];
    #pragma unroll
    for (int fr = 0; fr < 4; ++fr) {
      const int row = wr * 64 + fr * 16 + ln;
      af[fr] = *(const bf16x8*)&Hs[row * 256 + k0 + ((g ^ ((row >> 1) & 3)) * 8)];
    }
    #pragma unroll
    for (int fc = 0; fc < 2; ++fc) {
      const int col = wc * 32 + fc * 16 + ln;
      bfr[fc] = *(const bf16x8*)&Bs[col * 32 + ((g ^ ((col >> 1) & 3)) * 8)];
    }
    #pragma unroll
    for (int fr = 0; fr < 4; ++fr)
      #pragma unroll
      for (int fc = 0; fc < 2; ++fc)
        acc2[fr][fc] = __builtin_amdgcn_mfma_f32_16x16x32_bf16(af[fr], bfr[fc], acc2[fr][fc], 0, 0, 0);
    __syncthreads();
  }

  // ---- epilogue
  if (AGG) {
    const int b = (int)(t0 >> 8);
    const int s0 = (int)(t0 & 255);
    const int len = lens[b];
    #pragma unroll
    for (int fc = 0; fc < 2; ++fc) {
      const int col = wc * 32 + fc * 16 + ln;
      const float bb = b2[col];
      float sum = 0.0f;
      #pragma unroll
      for (int fr = 0; fr < 4; ++fr) {
        const int sbase = s0 + wr * 64 + fr * 16 + g4;
        #pragma unroll
        for (int r = 0; r < 4; ++r) {
          if (sbase + r < len) sum += fmaxf(acc2[fr][fc][r] + bb, 0.0f);
        }
      }
      sum += __shfl_xor(sum, 16, 64);
      sum += __shfl_xor(sum, 32, 64);
      if (g == 0) atomicAdd(&aggOut[(long)b * P_ + col], sum);
    }
  } else {
    #pragma unroll
    for (int fc = 0; fc < 2; ++fc) {
      const int col = wc * 32 + fc * 16 + ln;
      const float bb = b2[col];
      #pragma unroll
      for (int fr = 0; fr < 4; ++fr) {
        const long rbase = t0 + wr * 64 + fr * 16 + g4;
        #pragma unroll
        for (int r = 0; r < 4; ++r)
          outp[(rbase + r) * P_ + col] = (unsigned short)f2bf(fmaxf(acc2[fr][fc][r] + bb, 0.0f));
      }
    }
  }
}

// ---------------- fused attention (1024 threads): out = softmax(mask(A@B^T)) @ X ----------------
// blockIdx.z: z=0 beta (rows=f1), z=1 alpha (operands swapped).
__global__ __launch_bounds__(1024) void attend_fused(
    const unsigned short* __restrict__ f12, const unsigned short* __restrict__ x12T,
    const int* __restrict__ lens12, unsigned short* __restrict__ out12)
{
  __shared__ unsigned short As[128 * 32];
  __shared__ unsigned short Bs[256 * 32];
  __shared__ unsigned short Pt[128 * 256];
  __shared__ float redmax[128][8];
  __shared__ float redsum[128][8];

  const int tid = threadIdx.x;
  const int lane = tid & 63;
  const int w = tid >> 6;               // 0..15
  const int wr = w >> 3, wc = w & 7;    // 2 x 8
  const int b = blockIdx.y;
  const int z = blockIdx.z;
  const int i0 = blockIdx.x * 128;
  const int g = lane >> 4, ln = lane & 15;
  const int g4 = g * 4;

  const unsigned short* Afeat = f12 + (size_t)z * TOK_ * P_;
  const unsigned short* Bfeat = f12 + (size_t)(1 - z) * TOK_ * P_;
  const unsigned short* XT    = x12T + (size_t)(1 - z) * TOK_ * P_;
  unsigned short* outp        = out12 + (size_t)z * TOK_ * P_;
  const int l1 = lens12[z * B_ + b];
  const int l2 = lens12[(1 - z) * B_ + b];

  const unsigned short* Arows = Afeat + ((long)b * S_ + i0) * P_;
  const unsigned short* Brows = Bfeat + (long)b * S_ * P_;

  f32x4 acc[4][2];
  #pragma unroll
  for (int i = 0; i < 4; ++i)
    #pragma unroll
    for (int j = 0; j < 2; ++j) acc[i][j] = (f32x4){0.f, 0.f, 0.f, 0.f};

  // ---- phase 1: S = A @ B^T
  for (int k0 = 0; k0 < P_; k0 += 32) {
    if (tid < 512) {
      const int arow = tid >> 2, aks = tid & 3;
      bf16x8 v = *(const bf16x8*)(Arows + (long)arow * P_ + k0 + aks * 8);
      const int slot = aks ^ ((arow >> 1) & 3);
      *(bf16x8*)&As[arow * 32 + slot * 8] = v;
    }
    {
      const int col = tid >> 2, ks = tid & 3;
      bf16x8 v = *(const bf16x8*)(Brows + (long)col * P_ + k0 + ks * 8);
      const int slot = ks ^ ((col >> 1) & 3);
      *(bf16x8*)&Bs[col * 32 + slot * 8] = v;
    }
    __syncthreads();
    bf16x8 af[4], bfr[2];
    #pragma unroll
    for (int fr = 0; fr < 4; ++fr) {
      const int row = wr * 64 + fr * 16 + ln;
      af[fr] = *(const bf16x8*)&As[row * 32 + ((g ^ ((row >> 1) & 3)) * 8)];
    }
    #pragma unroll
    for (int fc = 0; fc < 2; ++fc) {
      const int col = wc * 32 + fc * 16 + ln;
      bfr[fc] = *(const bf16x8*)&Bs[col * 32 + ((g ^ ((col >> 1) & 3)) * 8)];
    }
    #pragma unroll
    for (int fr = 0; fr < 4; ++fr)
      #pragma unroll
      for (int fc = 0; fc < 2; ++fc)
        acc[fr][fc] = __builtin_amdgcn_mfma_f32_16x16x32_bf16(af[fr], bfr[fc], acc[fr][fc], 0, 0, 0);
    __syncthreads();
  }

  // ---- mask (multiplicative; masked entries keep exp(0) per reference)
  #pragma unroll
  for (int fc = 0; fc < 2; ++fc) {
    const int col = wc * 32 + fc * 16 + ln;
    const float mj = (col < l2) ? 1.0f : 0.0f;
    #pragma unroll
    for (int fr = 0; fr < 4; ++fr) {
      #pragma unroll
      for (int r = 0; r < 4; ++r) {
        const int rowg = i0 + wr * 64 + fr * 16 + g4 + r;
        acc[fr][fc][r] *= (rowg < l1) ? mj : 0.0f;
      }
    }
  }
  // per-wave (32-col) max -> LDS
  #pragma unroll
  for (int fr = 0; fr < 4; ++fr) {
    #pragma unroll
    for (int r = 0; r < 4; ++r) {
      float m = fmaxf(acc[fr][0][r], acc[fr][1][r]);
      m = fmaxf(m, __shfl_xor(m, 1, 64));
      m = fmaxf(m, __shfl_xor(m, 2, 64));
      m = fmaxf(m, __shfl_xor(m, 4, 64));
      m = fmaxf(m, __shfl_xor(m, 8, 64));
      if (ln == 0) redmax[wr * 64 + fr * 16 + g4 + r][wc] = m;
    }
  }
  __syncthreads();
  #pragma unroll
  for (int fr = 0; fr < 4; ++fr) {
    #pragma unroll
    for (int r = 0; r < 4; ++r) {
      const int lr = wr * 64 + fr * 16 + g4 + r;
      const float4 a4 = *(const float4*)&redmax[lr][0];
      const float4 b4 = *(const float4*)&redmax[lr][4];
      const float m = fmaxf(fmaxf(fmaxf(a4.x, a4.y), fmaxf(a4.z, a4.w)),
                            fmaxf(fmaxf(b4.x, b4.y), fmaxf(b4.z, b4.w)));
      float s = 0.0f;
      #pragma unroll
      for (int fc = 0; fc < 2; ++fc) {
        const float e = __expf(acc[fr][fc][r] - m);
        acc[fr][fc][r] = e;
        s += e;
      }
      s += __shfl_xor(s, 1, 64);
      s += __shfl_xor(s, 2, 64);
      s += __shfl_xor(s, 4, 64);
      s += __shfl_xor(s, 8, 64);
      if (ln == 0) redsum[lr][wc] = s;
    }
  }
  __syncthreads();
  // normalize + write P tile (bf16, swizzled)
  #pragma unroll
  for (int fr = 0; fr < 4; ++fr) {
    #pragma unroll
    for (int r = 0; r < 4; ++r) {
      const int lr = wr * 64 + fr * 16 + g4 + r;
      const float4 a4 = *(const float4*)&redsum[lr][0];
      const float4 b4 = *(const float4*)&redsum[lr][4];
      const float inv = 1.0f / (a4.x + a4.y + a4.z + a4.w + b4.x + b4.y + b4.z + b4.w);
      #pragma unroll
      for (int fc = 0; fc < 2; ++fc) {
        const int col = wc * 32 + fc * 16 + ln;
        Pt[lr * 256 + ((col & ~31) | ((((col >> 3) & 3) ^ ((lr >> 1) & 3)) << 3) | (col & 7))] =
            (unsigned short)f2bf(acc[fr][fc][r] * inv);
      }
    }
  }

  // ---- phase 2: out = P @ X
  f32x4 acc2[4][2];
  #pragma unroll
  for (int i = 0; i < 4; ++i)
    #pragma unroll
    for (int j = 0; j < 2; ++j) acc2[i][j] = (f32x4){0.f, 0.f, 0.f, 0.f};
  const unsigned short* XTb = XT + (long)b * P_ * S_;
  for (int k0 = 0; k0 < S_; k0 += 32) {
    {
      const int col = tid >> 2, ks = tid & 3;
      bf16x8 v = *(const bf16x8*)(XTb + (long)col * S_ + k0 + ks * 8);
      const int slot = ks ^ ((col >> 1) & 3);
      *(bf16x8*)&Bs[col * 32 + slot * 8] = v;
    }
    __syncthreads();   // first iteration also covers Pt writes
    bf16x8 af[4], bfr[2];
    #pragma unroll
    for (int fr = 0; fr < 4; ++fr) {
      const int row = wr * 64 + fr * 16 + ln;
      af[fr] = *(const bf16x8*)&Pt[row * 256 + k0 + ((g ^ ((row >> 1) & 3)) * 8)];
    }
    #pragma unroll
    for (int fc = 0; fc < 2; ++fc) {
      const int col = wc * 32 + fc * 16 + ln;
      bfr[fc] = *(const bf16x8*)&Bs[col * 32 + ((g ^ ((col >> 1) & 3)) * 8)];
    }
    #pragma unroll
    for (int fr = 0; fr < 4; ++fr)
      #pragma unroll
      for (int fc = 0; fc < 2; ++fc)
        acc2[fr][fc] = __builtin_amdgcn_mfma_f32_16x16x32_bf16(af[fr], bfr[fc], acc2[fr][fc], 0, 0, 0);
    __syncthreads();
  }

  #pragma unroll
  for (int fc = 0; fc < 2; ++fc) {
    const int col = wc * 32 + fc * 16 + ln;
    #pragma unroll
    for (int fr = 0; fr < 4; ++fr) {
      const long rbase = (long)b * S_ + i0 + wr * 64 + fr * 16 + g4;
      #pragma unroll
      for (int r = 0; r < 4; ++r)
        outp[(rbase + r) * P_ + col] = (unsigned short)f2bf(acc2[fr][fc][r]);
    }
  }
}

// ---------------- final head (fp32) ----------------
__global__ __launch_bounds__(256) void head_kernel(
    const float* __restrict__ v1s, const float* __restrict__ v2s,
    const float* __restrict__ HW1p, const float* __restrict__ Hb1p,
    const float* __restrict__ HW2p, const float* __restrict__ Hb2p,
    const float* __restrict__ Wout, const float* __restrict__ bout,
    float* __restrict__ y)
{
  __shared__ float xin[2 * P_];
  __shared__ float h[P_];
  const int b = blockIdx.x;
  const int tid = threadIdx.x;
  xin[tid] = v1s[(long)b * P_ + tid];
  xin[P_ + tid] = v2s[(long)b * P_ + tid];
  __syncthreads();
  float acc = Hb1p[tid];
  for (int e = 0; e < 2 * P_; ++e) acc += xin[e] * HW1p[(long)e * P_ + tid];
  h[tid] = fmaxf(acc, 0.0f);
  __syncthreads();
  float acc2 = Hb2p[tid];
  for (int e = 0; e < P_; ++e) acc2 += h[e] * HW2p[(long)e * P_ + tid];
  const float h2 = fmaxf(acc2, 0.0f);
  __syncthreads();
  xin[tid] = h2;
  __syncthreads();
  if (tid < C_) {
    float a = bout[tid];
    for (int d = 0; d < D_; ++d) a += xin[d] * Wout[d * C_ + tid];
    y[(long)b * C_ + tid] = a;
  }
}

// ---------------- launch ----------------
extern "C" void kernel_launch(void* const* d_in, const int* in_sizes, int n_in,
                              void* d_out, int out_size, void* d_ws, size_t ws_size,
                              hipStream_t stream)
{
  const int*   x1    = (const int*)d_in[0];
  const int*   x2    = (const int*)d_in[1];
  const int*   len1  = (const int*)d_in[2];
  const int*   len2  = (const int*)d_in[3];
  const float* emb   = (const float*)d_in[4];
  const float* Wproj = (const float*)d_in[5];
  const float* FW1   = (const float*)d_in[6];
  const float* Fb1   = (const float*)d_in[7];
  const float* FW2   = (const float*)d_in[8];
  const float* Fb2   = (const float*)d_in[9];
  const float* GW1   = (const float*)d_in[10];
  const float* Gb1   = (const float*)d_in[11];
  const float* GW2   = (const float*)d_in[12];
  const float* Gb2   = (const float*)d_in[13];
  const float* HW1   = (const float*)d_in[14];
  const float* Hb1   = (const float*)d_in[15];
  const float* HW2   = (const float*)d_in[16];
  const float* Hb2   = (const float*)d_in[17];
  const float* Wout  = (const float*)d_in[18];
  const float* bout  = (const float*)d_in[19];
  float* out = (float*)d_out;

  float* ws = (float*)d_ws;
  size_t o = 0;
  auto alloc = [&](size_t n) { float* p = ws + o; o += n; return p; };
  float* v12    = alloc((size_t)2 * B_ * P_);
  float* invn12 = alloc((size_t)2 * TOK_);
  float* HW1p   = alloc((size_t)2 * P_ * P_);
  float* HW2p   = alloc((size_t)P_ * P_);
  float* biases = alloc((size_t)6 * 256);
  int* ids12  = (int*)alloc((size_t)2 * TOK_);
  int* lens12 = (int*)alloc(2 * B_);
  unsigned short* us = (unsigned short*)(ws + o);
  size_t uo = 0;
  auto ualloc = [&](size_t n) { unsigned short* p = us + uo; uo += n; return p; };
  unsigned short* x12b  = ualloc((size_t)2 * TOK_ * P_);
  unsigned short* f12b  = ualloc((size_t)2 * TOK_ * P_);
  unsigned short* ba12b = ualloc((size_t)2 * TOK_ * P_);
  unsigned short* x12T  = ualloc((size_t)2 * TOK_ * P_);
  unsigned short* WpT   = ualloc((size_t)P_ * 320);
  unsigned short* FW1T  = ualloc((size_t)P_ * P_);
  unsigned short* FW2T  = ualloc((size_t)P_ * P_);
  unsigned short* GW1T  = ualloc((size_t)P_ * 2 * P_);
  unsigned short* GW2T  = ualloc((size_t)P_ * P_);
  if (o * sizeof(float) + uo * sizeof(unsigned short) > ws_size) return;

  float* Fb1p = biases + 0;
  float* Fb2p = biases + 256;
  float* Gb1p = biases + 512;
  float* Gb2p = biases + 768;
  float* Hb1p = biases + 1024;
  float* Hb2p = biases + 1280;
  float* v1s = v12;
  float* v2s = v12 + (size_t)B_ * P_;

  // 1. all prep in one launch
  prep_all<<<2887, 256, 0, stream>>>(
      Wproj, FW1, FW2, GW1, GW2, HW1, HW2,
      Fb1, Fb2, Gb1, Gb2, Hb1, Hb2,
      x1, x2, len1, len2,
      WpT, FW1T, FW2T, GW1T, GW2T, HW1p, HW2p, biases, v12, ids12, lens12);

  // 2. embedding norms
  invnorm_kernel<<<2 * TOK_ / 4, 256, 0, stream>>>(ids12, emb, invn12);

  // 3. merged projection (gather GEMM, K=320)
  proj_mfma<<<2 * TOK_ / 128, 512, 0, stream>>>(ids12, emb, invn12, WpT, x12b, 320);

  // 4. transposed projections for attend PV
  {
    dim3 grid(2 * B_, 4, 4);
    transpose_bf16<<<grid, 256, 0, stream>>>(x12b, x12T);
  }

  // 5. fused F MLP (both layers, 2*TOK rows)
  fused_mlp<0, false><<<2 * TOK_ / 128, 1024, 0, stream>>>(
      x12b, nullptr, FW1T, Fb1p, FW2T, Fb2p, f12b, nullptr, nullptr, P_);

  // 6. fused attention, both directions
  {
    dim3 grid(S_ / 128, B_, 2);
    attend_fused<<<grid, 1024, 0, stream>>>(f12b, x12T, lens12, ba12b);
  }

  // 7. fused G MLP + masked aggregation
  fused_mlp<2, true><<<2 * TOK_ / 128, 1024, 0, stream>>>(
      x12b, ba12b, GW1T, Gb1p, GW2T, Gb2p, nullptr, v12, lens12, 2 * P_);

  // 8. head
  head_kernel<<<B_, 256, 0, stream>>>(v1s, v2s, HW1p, Hb1p, HW2p, Hb2p, Wout, bout, out);
}

// Round 8
// 394.403 us; speedup vs baseline: 3.1598x; 1.0081x over previous
//
#include <hip/hip_runtime.h>
#include <math.h>

#define B_ 128
#define S_ 256
#define V_ 50000
#define E_ 300
#define D_ 200
#define C_ 3
#define P_ 256            // padded D
#define TOK_ (B_*S_)      // 32768

typedef __attribute__((ext_vector_type(8))) short bf16x8;
typedef __attribute__((ext_vector_type(4))) float f32x4;

static __device__ __forceinline__ short f2bf(float f) {
  unsigned u = __builtin_bit_cast(unsigned, f);
  u += 0x7fffu + ((u >> 16) & 1u);   // RNE
  return (short)(u >> 16);
}

// ---------------- single fused prep kernel (weights, biases, ids, lens, zero) ----------------
__global__ __launch_bounds__(256) void prep_all(
    const float* __restrict__ Wproj, const float* __restrict__ FW1,
    const float* __restrict__ FW2, const float* __restrict__ GW1,
    const float* __restrict__ GW2, const float* __restrict__ HW1,
    const float* __restrict__ HW2,
    const float* __restrict__ Fb1, const float* __restrict__ Fb2,
    const float* __restrict__ Gb1, const float* __restrict__ Gb2,
    const float* __restrict__ Hb1, const float* __restrict__ Hb2,
    const int* __restrict__ x1, const int* __restrict__ x2,
    const int* __restrict__ len1, const int* __restrict__ len2,
    unsigned short* __restrict__ WpT, unsigned short* __restrict__ FW1T,
    unsigned short* __restrict__ FW2T, unsigned short* __restrict__ GW1T,
    unsigned short* __restrict__ GW2T, float* __restrict__ HW1p,
    float* __restrict__ HW2p, float* __restrict__ biases,
    float* __restrict__ v12, int* __restrict__ ids12, int* __restrict__ lens12)
{
  const int blk = blockIdx.x;
  const int tid = threadIdx.x;
  if (blk < 320) {
    int idx = blk * 256 + tid;
    int n = idx / 320, k = idx - n * 320;
    WpT[idx] = (unsigned short)f2bf((k < E_ && n < D_) ? Wproj[k * D_ + n] : 0.0f);
  } else if (blk < 576) {
    int idx = (blk - 320) * 256 + tid;
    int n = idx >> 8, k = idx & 255;
    FW1T[idx] = (unsigned short)f2bf((k < D_ && n < D_) ? FW1[k * D_ + n] : 0.0f);
  } else if (blk < 832) {
    int idx = (blk - 576) * 256 + tid;
    int n = idx >> 8, k = idx & 255;
    FW2T[idx] = (unsigned short)f2bf((k < D_ && n < D_) ? FW2[k * D_ + n] : 0.0f);
  } else if (blk < 1088) {
    int idx = (blk - 832) * 256 + tid;
    int n = idx >> 8, k = idx & 255;
    GW2T[idx] = (unsigned short)f2bf((k < D_ && n < D_) ? GW2[k * D_ + n] : 0.0f);
  } else if (blk < 1600) {
    int idx = (blk - 1088) * 256 + tid;
    int n = idx >> 9, k = idx & 511;
    int sk = (k < 256) ? ((k < D_) ? k : -1) : (((k - 256) < D_) ? (D_ + k - 256) : -1);
    GW1T[idx] = (unsigned short)f2bf((sk >= 0 && n < D_) ? GW1[sk * D_ + n] : 0.0f);
  } else if (blk < 2112) {
    int idx = (blk - 1600) * 256 + tid;
    int r = idx >> 8, c = idx & 255;
    int sr = (r < D_) ? r : ((r >= 256 && r < 256 + D_) ? (r - 56) : -1);
    HW1p[idx] = (sr >= 0 && c < D_) ? HW1[sr * D_ + c] : 0.0f;
  } else if (blk < 2368) {
    int idx = (blk - 2112) * 256 + tid;
    int r = idx >> 8, c = idx & 255;
    HW2p[idx] = (r < D_ && c < D_) ? HW2[r * D_ + c] : 0.0f;
  } else if (blk < 2374) {
    int j = blk - 2368;
    const float* src = (j == 0) ? Fb1 : (j == 1) ? Fb2 : (j == 2) ? Gb1
                      : (j == 3) ? Gb2 : (j == 4) ? Hb1 : Hb2;
    biases[j * 256 + tid] = (tid < D_) ? src[tid] : 0.0f;
  } else if (blk < 2630) {
    v12[(blk - 2374) * 256 + tid] = 0.0f;
  } else if (blk < 2886) {
    int idx = (blk - 2630) * 256 + tid;
    ids12[idx] = (idx < TOK_) ? x1[idx] : x2[idx - TOK_];
  } else {
    if (tid < B_) lens12[tid] = len1[tid];
    else if (tid < 2 * B_) lens12[tid] = len2[tid - B_];
  }
}

// ---------------- batch transpose bf16: out[b][d][s] = in[b][s][d] ----------------
__global__ __launch_bounds__(256) void transpose_bf16(
    const unsigned short* __restrict__ in, unsigned short* __restrict__ outp) {
  __shared__ unsigned short t[64][66];
  const int b = blockIdx.x;
  const int r0 = blockIdx.y * 64, c0 = blockIdx.z * 64;
  const unsigned short* src = in + (long)b * S_ * P_;
  unsigned short* dst = outp + (long)b * P_ * S_;
  const int tx = threadIdx.x & 63, ty = threadIdx.x >> 6;
  #pragma unroll
  for (int i = 0; i < 16; ++i)
    t[ty * 16 + i][tx] = src[(long)(r0 + ty * 16 + i) * P_ + c0 + tx];
  __syncthreads();
  #pragma unroll
  for (int i = 0; i < 16; ++i)
    dst[(long)(c0 + ty * 16 + i) * S_ + r0 + tx] = t[tx][ty * 16 + i];
}

// ---------------- projection GEMM (gather + fused L2-norm): 512 threads, 128-row tile ----------------
__global__ __launch_bounds__(512) void proj_mfma(
    const int* __restrict__ ids, const float* __restrict__ emb,
    const unsigned short* __restrict__ WT,
    unsigned short* __restrict__ outp, int K)
{
  __shared__ unsigned short As[128 * 32];
  __shared__ unsigned short Bs[256 * 32];
  __shared__ float invn_s[128];
  const int tid = threadIdx.x;
  const int lane = tid & 63;
  const int w = tid >> 6;
  const int wr = w >> 2, wc = w & 3;
  const long t0 = (long)blockIdx.x * 128;
  const int g = lane >> 4, ln = lane & 15;

  // fused per-row inverse norm: 4 lanes per row, interleaved reads
  {
    const int r = tid >> 2, q = tid & 3;
    const long base = (long)ids[t0 + r] * E_;
    float ss = 0.0f;
    for (int e = q; e < E_; e += 4) { float v = emb[base + e]; ss += v * v; }
    ss += __shfl_xor(ss, 1, 64);
    ss += __shfl_xor(ss, 2, 64);
    if (q == 0) invn_s[r] = 1.0f / sqrtf(ss);
  }
  __syncthreads();

  f32x4 acc[4][4];
  #pragma unroll
  for (int i = 0; i < 4; ++i)
    #pragma unroll
    for (int j = 0; j < 4; ++j) acc[i][j] = (f32x4){0.f, 0.f, 0.f, 0.f};

  const int arow = tid >> 2, aks = tid & 3;
  for (int k0 = 0; k0 < K; k0 += 32) {
    {
      const long base = (long)ids[t0 + arow] * E_;
      const float inv = invn_s[arow];
      const int kb = k0 + aks * 8;
      short tmp[8];
      #pragma unroll
      for (int i = 0; i < 8; ++i) {
        const int k = kb + i;
        tmp[i] = f2bf((k < E_) ? emb[base + k] * inv : 0.0f);
      }
      bf16x8 v;
      #pragma unroll
      for (int i = 0; i < 8; ++i) v[i] = tmp[i];
      const int slot = aks ^ ((arow >> 1) & 3);
      *(bf16x8*)&As[arow * 32 + slot * 8] = v;
    }
    #pragma unroll
    for (int cc = 0; cc < 2; ++cc) {
      const int c = tid + cc * 512;
      const int col = c >> 2, ks = c & 3;
      bf16x8 v = *(const bf16x8*)(WT + (long)col * K + k0 + ks * 8);
      const int slot = ks ^ ((col >> 1) & 3);
      *(bf16x8*)&Bs[col * 32 + slot * 8] = v;
    }
    __syncthreads();
    bf16x8 af[4], bfr[4];
    #pragma unroll
    for (int fr = 0; fr < 4; ++fr) {
      const int row = wr * 64 + fr * 16 + ln;
      af[fr] = *(const bf16x8*)&As[row * 32 + ((g ^ ((row >> 1) & 3)) * 8)];
    }
    #pragma unroll
    for (int fc = 0; fc < 4; ++fc) {
      const int col = wc * 64 + fc * 16 + ln;
      bfr[fc] = *(const bf16x8*)&Bs[col * 32 + ((g ^ ((col >> 1) & 3)) * 8)];
    }
    #pragma unroll
    for (int fr = 0; fr < 4; ++fr)
      #pragma unroll
      for (int fc = 0; fc < 4; ++fc)
        acc[fr][fc] = __builtin_amdgcn_mfma_f32_16x16x32_bf16(af[fr], bfr[fc], acc[fr][fc], 0, 0, 0);
    __syncthreads();
  }
  const int g4 = g * 4;
  #pragma unroll
  for (int fc = 0; fc < 4; ++fc) {
    const int col = wc * 64 + fc * 16 + ln;
    #pragma unroll
    for (int fr = 0; fr < 4; ++fr) {
      const long rbase = t0 + wr * 64 + fr * 16 + g4;
      #pragma unroll
      for (int r = 0; r < 4; ++r)
        outp[(rbase + r) * P_ + col] = (unsigned short)f2bf(acc[fr][fc][r]);
    }
  }
}

// ---------------- fused two-layer MLP: 64-row tile, 512 threads (8 waves 1x8) ----------------
// out = relu(relu(A@W1+b1)@W2+b2); MODE1 0: A=A1 (K1=256); MODE1 2: A=concat(A1,A2) (K1=512).
// AGG: masked column-sum -> atomicAdd aggOut. LDS 52KB -> 3 blocks/CU.
template<int MODE1, bool AGG>
__global__ __launch_bounds__(512) void fused_mlp(
    const unsigned short* __restrict__ A1, const unsigned short* __restrict__ A2,
    const unsigned short* __restrict__ W1T, const float* __restrict__ b1,
    const unsigned short* __restrict__ W2T, const float* __restrict__ b2,
    unsigned short* __restrict__ outp, float* __restrict__ aggOut,
    const int* __restrict__ lens, int K1)
{
  __shared__ unsigned short As[64 * 32];
  __shared__ unsigned short Bs[256 * 32];
  __shared__ unsigned short Hs[64 * 256];
  const int tid = threadIdx.x;
  const int lane = tid & 63;
  const int w = tid >> 6;               // 0..7 (col groups of 32)
  const long t0 = (long)blockIdx.x * 64;
  const int g = lane >> 4, ln = lane & 15;
  const int g4 = g * 4;

  f32x4 acc[4][2];
  #pragma unroll
  for (int i = 0; i < 4; ++i)
    #pragma unroll
    for (int j = 0; j < 2; ++j) acc[i][j] = (f32x4){0.f, 0.f, 0.f, 0.f};

  // ---- stage 1: H = relu(A @ W1 + b1)
  for (int k0 = 0; k0 < K1; k0 += 32) {
    if (tid < 256) {
      const int arow = tid >> 2, aks = tid & 3;
      bf16x8 v;
      if (MODE1 == 2) {
        const unsigned short* src = (k0 < P_) ? (A1 + (t0 + arow) * P_ + k0)
                                              : (A2 + (t0 + arow) * P_ + (k0 - P_));
        v = *(const bf16x8*)(src + aks * 8);
      } else {
        v = *(const bf16x8*)(A1 + (t0 + arow) * P_ + k0 + aks * 8);
      }
      const int slot = aks ^ ((arow >> 1) & 3);
      *(bf16x8*)&As[arow * 32 + slot * 8] = v;
    }
    #pragma unroll
    for (int cc = 0; cc < 2; ++cc) {
      const int c = tid + cc * 512;
      const int col = c >> 2, ks = c & 3;
      bf16x8 v = *(const bf16x8*)(W1T + (long)col * K1 + k0 + ks * 8);
      const int slot = ks ^ ((col >> 1) & 3);
      *(bf16x8*)&Bs[col * 32 + slot * 8] = v;
    }
    __syncthreads();
    bf16x8 af[4], bfr[2];
    #pragma unroll
    for (int fr = 0; fr < 4; ++fr) {
      const int row = fr * 16 + ln;
      af[fr] = *(const bf16x8*)&As[row * 32 + ((g ^ ((row >> 1) & 3)) * 8)];
    }
    #pragma unroll
    for (int fc = 0; fc < 2; ++fc) {
      const int col = w * 32 + fc * 16 + ln;
      bfr[fc] = *(const bf16x8*)&Bs[col * 32 + ((g ^ ((col >> 1) & 3)) * 8)];
    }
    #pragma unroll
    for (int fr = 0; fr < 4; ++fr)
      #pragma unroll
      for (int fc = 0; fc < 2; ++fc)
        acc[fr][fc] = __builtin_amdgcn_mfma_f32_16x16x32_bf16(af[fr], bfr[fc], acc[fr][fc], 0, 0, 0);
    __syncthreads();
  }

  // write H to LDS (bf16, A-tile swizzle)
  #pragma unroll
  for (int fc = 0; fc < 2; ++fc) {
    const int col = w * 32 + fc * 16 + ln;
    const float bb = b1[col];
    #pragma unroll
    for (int fr = 0; fr < 4; ++fr) {
      #pragma unroll
      for (int r = 0; r < 4; ++r) {
        const int lr = fr * 16 + g4 + r;
        const float v = fmaxf(acc[fr][fc][r] + bb, 0.0f);
        Hs[lr * 256 + ((col & ~31) | ((((col >> 3) & 3) ^ ((lr >> 1) & 3)) << 3) | (col & 7))] =
            (unsigned short)f2bf(v);
      }
    }
  }

  // ---- stage 2: O = relu(H @ W2 + b2)
  f32x4 acc2[4][2];
  #pragma unroll
  for (int i = 0; i < 4; ++i)
    #pragma unroll
    for (int j = 0; j < 2; ++j) acc2[i][j] = (f32x4){0.f, 0.f, 0.f, 0.f};

  for (int k0 = 0; k0 < 256; k0 += 32) {
    #pragma unroll
    for (int cc = 0; cc < 2; ++cc) {
      const int c = tid + cc * 512;
      const int col = c >> 2, ks = c & 3;
      bf16x8 v = *(const bf16x8*)(W2T + (long)col * 256 + k0 + ks * 8);
      const int slot = ks ^ ((col >> 1) & 3);
      *(bf16x8*)&Bs[col * 32 + slot * 8] = v;
    }
    __syncthreads();   // covers H writes on first iteration
    bf16x8 af[4], bfr[2];
    #pragma unroll
    for (int fr = 0; fr < 4; ++fr) {
      const int row = fr * 16 + ln;
      af[fr] = *(const bf16x8*)&Hs[row * 256 + k0 + ((g ^ ((row >> 1) & 3)) * 8)];
    }
    #pragma unroll
    for (int fc = 0; fc < 2; ++fc) {
      const int col = w * 32 + fc * 16 + ln;
      bfr[fc] = *(const bf16x8*)&Bs[col * 32 + ((g ^ ((col >> 1) & 3)) * 8)];
    }
    #pragma unroll
    for (int fr = 0; fr < 4; ++fr)
      #pragma unroll
      for (int fc = 0; fc < 2; ++fc)
        acc2[fr][fc] = __builtin_amdgcn_mfma_f32_16x16x32_bf16(af[fr], bfr[fc], acc2[fr][fc], 0, 0, 0);
    __syncthreads();
  }

  // ---- epilogue
  if (AGG) {
    const int b = (int)(t0 >> 8);
    const int s0 = (int)(t0 & 255);
    const int len = lens[b];
    #pragma unroll
    for (int fc = 0; fc < 2; ++fc) {
      const int col = w * 32 + fc * 16 + ln;
      const float bb = b2[col];
      float sum = 0.0f;
      #pragma unroll
      for (int fr = 0; fr < 4; ++fr) {
        const int sbase = s0 + fr * 16 + g4;
        #pragma unroll
        for (int r = 0; r < 4; ++r) {
          if (sbase + r < len) sum += fmaxf(acc2[fr][fc][r] + bb, 0.0f);
        }
      }
      sum += __shfl_xor(sum, 16, 64);
      sum += __shfl_xor(sum, 32, 64);
      if (g == 0) atomicAdd(&aggOut[(long)b * P_ + col], sum);
    }
  } else {
    #pragma unroll
    for (int fc = 0; fc < 2; ++fc) {
      const int col = w * 32 + fc * 16 + ln;
      const float bb = b2[col];
      #pragma unroll
      for (int fr = 0; fr < 4; ++fr) {
        const long rbase = t0 + fr * 16 + g4;
        #pragma unroll
        for (int r = 0; r < 4; ++r)
          outp[(rbase + r) * P_ + col] = (unsigned short)f2bf(fmaxf(acc2[fr][fc][r] + bb, 0.0f));
      }
    }
  }
}

// ---------------- fused attention: 64-row tile, 512 threads (8 waves 1x8) ----------------
// blockIdx.z: z=0 beta (rows=f1), z=1 alpha (operands swapped). LDS 56KB -> 2 blocks/CU.
__global__ __launch_bounds__(512) void attend_fused(
    const unsigned short* __restrict__ f12, const unsigned short* __restrict__ x12T,
    const int* __restrict__ lens12, unsigned short* __restrict__ out12)
{
  __shared__ unsigned short As[64 * 32];
  __shared__ unsigned short Bs[256 * 32];
  __shared__ unsigned short Pt[64 * 256];
  __shared__ float redmax[64][8];
  __shared__ float redsum[64][8];

  const int tid = threadIdx.x;
  const int lane = tid & 63;
  const int w = tid >> 6;               // 0..7 (col groups of 32)
  const int b = blockIdx.y;
  const int z = blockIdx.z;
  const int i0 = blockIdx.x * 64;
  const int g = lane >> 4, ln = lane & 15;
  const int g4 = g * 4;

  const unsigned short* Afeat = f12 + (size_t)z * TOK_ * P_;
  const unsigned short* Bfeat = f12 + (size_t)(1 - z) * TOK_ * P_;
  const unsigned short* XT    = x12T + (size_t)(1 - z) * TOK_ * P_;
  unsigned short* outp        = out12 + (size_t)z * TOK_ * P_;
  const int l1 = lens12[z * B_ + b];
  const int l2 = lens12[(1 - z) * B_ + b];

  const unsigned short* Arows = Afeat + ((long)b * S_ + i0) * P_;
  const unsigned short* Brows = Bfeat + (long)b * S_ * P_;

  f32x4 acc[4][2];
  #pragma unroll
  for (int i = 0; i < 4; ++i)
    #pragma unroll
    for (int j = 0; j < 2; ++j) acc[i][j] = (f32x4){0.f, 0.f, 0.f, 0.f};

  // ---- phase 1: S = A @ B^T
  for (int k0 = 0; k0 < P_; k0 += 32) {
    if (tid < 256) {
      const int arow = tid >> 2, aks = tid & 3;
      bf16x8 v = *(const bf16x8*)(Arows + (long)arow * P_ + k0 + aks * 8);
      const int slot = aks ^ ((arow >> 1) & 3);
      *(bf16x8*)&As[arow * 32 + slot * 8] = v;
    }
    #pragma unroll
    for (int cc = 0; cc < 2; ++cc) {
      const int c = tid + cc * 512;
      const int col = c >> 2, ks = c & 3;
      bf16x8 v = *(const bf16x8*)(Brows + (long)col * P_ + k0 + ks * 8);
      const int slot = ks ^ ((col >> 1) & 3);
      *(bf16x8*)&Bs[col * 32 + slot * 8] = v;
    }
    __syncthreads();
    bf16x8 af[4], bfr[2];
    #pragma unroll
    for (int fr = 0; fr < 4; ++fr) {
      const int row = fr * 16 + ln;
      af[fr] = *(const bf16x8*)&As[row * 32 + ((g ^ ((row >> 1) & 3)) * 8)];
    }
    #pragma unroll
    for (int fc = 0; fc < 2; ++fc) {
      const int col = w * 32 + fc * 16 + ln;
      bfr[fc] = *(const bf16x8*)&Bs[col * 32 + ((g ^ ((col >> 1) & 3)) * 8)];
    }
    #pragma unroll
    for (int fr = 0; fr < 4; ++fr)
      #pragma unroll
      for (int fc = 0; fc < 2; ++fc)
        acc[fr][fc] = __builtin_amdgcn_mfma_f32_16x16x32_bf16(af[fr], bfr[fc], acc[fr][fc], 0, 0, 0);
    __syncthreads();
  }

  // ---- mask (multiplicative; masked entries keep exp(0) per reference)
  #pragma unroll
  for (int fc = 0; fc < 2; ++fc) {
    const int col = w * 32 + fc * 16 + ln;
    const float mj = (col < l2) ? 1.0f : 0.0f;
    #pragma unroll
    for (int fr = 0; fr < 4; ++fr) {
      #pragma unroll
      for (int r = 0; r < 4; ++r) {
        const int rowg = i0 + fr * 16 + g4 + r;
        acc[fr][fc][r] *= (rowg < l1) ? mj : 0.0f;
      }
    }
  }
  // per-wave (32-col) max -> LDS
  #pragma unroll
  for (int fr = 0; fr < 4; ++fr) {
    #pragma unroll
    for (int r = 0; r < 4; ++r) {
      float m = fmaxf(acc[fr][0][r], acc[fr][1][r]);
      m = fmaxf(m, __shfl_xor(m, 1, 64));
      m = fmaxf(m, __shfl_xor(m, 2, 64));
      m = fmaxf(m, __shfl_xor(m, 4, 64));
      m = fmaxf(m, __shfl_xor(m, 8, 64));
      if (ln == 0) redmax[fr * 16 + g4 + r][w] = m;
    }
  }
  __syncthreads();
  #pragma unroll
  for (int fr = 0; fr < 4; ++fr) {
    #pragma unroll
    for (int r = 0; r < 4; ++r) {
      const int lr = fr * 16 + g4 + r;
      const float4 a4 = *(const float4*)&redmax[lr][0];
      const float4 b4 = *(const float4*)&redmax[lr][4];
      const float m = fmaxf(fmaxf(fmaxf(a4.x, a4.y), fmaxf(a4.z, a4.w)),
                            fmaxf(fmaxf(b4.x, b4.y), fmaxf(b4.z, b4.w)));
      float s = 0.0f;
      #pragma unroll
      for (int fc = 0; fc < 2; ++fc) {
        const float e = __expf(acc[fr][fc][r] - m);
        acc[fr][fc][r] = e;
        s += e;
      }
      s += __shfl_xor(s, 1, 64);
      s += __shfl_xor(s, 2, 64);
      s += __shfl_xor(s, 4, 64);
      s += __shfl_xor(s, 8, 64);
      if (ln == 0) redsum[lr][w] = s;
    }
  }
  __syncthreads();
  // normalize + write P tile (bf16, swizzled)
  #pragma unroll
  for (int fr = 0; fr < 4; ++fr) {
    #pragma unroll
    for (int r = 0; r < 4; ++r) {
      const int lr = fr * 16 + g4 + r;
      const float4 a4 = *(const float4*)&redsum[lr][0];
      const float4 b4 = *(const float4*)&redsum[lr][4];
      const float inv = 1.0f / (a4.x + a4.y + a4.z + a4.w + b4.x + b4.y + b4.z + b4.w);
      #pragma unroll
      for (int fc = 0; fc < 2; ++fc) {
        const int col = w * 32 + fc * 16 + ln;
        Pt[lr * 256 + ((col & ~31) | ((((col >> 3) & 3) ^ ((lr >> 1) & 3)) << 3) | (col & 7))] =
            (unsigned short)f2bf(acc[fr][fc][r] * inv);
      }
    }
  }

  // ---- phase 2: out = P @ X
  f32x4 acc2[4][2];
  #pragma unroll
  for (int i = 0; i < 4; ++i)
    #pragma unroll
    for (int j = 0; j < 2; ++j) acc2[i][j] = (f32x4){0.f, 0.f, 0.f, 0.f};
  const unsigned short* XTb = XT + (long)b * P_ * S_;
  for (int k0 = 0; k0 < S_; k0 += 32) {
    #pragma unroll
    for (int cc = 0; cc < 2; ++cc) {
      const int c = tid + cc * 512;
      const int col = c >> 2, ks = c & 3;
      bf16x8 v = *(const bf16x8*)(XTb + (long)col * S_ + k0 + ks * 8);
      const int slot = ks ^ ((col >> 1) & 3);
      *(bf16x8*)&Bs[col * 32 + slot * 8] = v;
    }
    __syncthreads();   // first iteration also covers Pt writes
    bf16x8 af[4], bfr[2];
    #pragma unroll
    for (int fr = 0; fr < 4; ++fr) {
      const int row = fr * 16 + ln;
      af[fr] = *(const bf16x8*)&Pt[row * 256 + k0 + ((g ^ ((row >> 1) & 3)) * 8)];
    }
    #pragma unroll
    for (int fc = 0; fc < 2; ++fc) {
      const int col = w * 32 + fc * 16 + ln;
      bfr[fc] = *(const bf16x8*)&Bs[col * 32 + ((g ^ ((col >> 1) & 3)) * 8)];
    }
    #pragma unroll
    for (int fr = 0; fr < 4; ++fr)
      #pragma unroll
      for (int fc = 0; fc < 2; ++fc)
        acc2[fr][fc] = __builtin_amdgcn_mfma_f32_16x16x32_bf16(af[fr], bfr[fc], acc2[fr][fc], 0, 0, 0);
    __syncthreads();
  }

  #pragma unroll
  for (int fc = 0; fc < 2; ++fc) {
    const int col = w * 32 + fc * 16 + ln;
    #pragma unroll
    for (int fr = 0; fr < 4; ++fr) {
      const long rbase = (long)b * S_ + i0 + fr * 16 + g4;
      #pragma unroll
      for (int r = 0; r < 4; ++r)
        outp[(rbase + r) * P_ + col] = (unsigned short)f2bf(acc2[fr][fc][r]);
    }
  }
}

// ---------------- final head (fp32) ----------------
__global__ __launch_bounds__(256) void head_kernel(
    const float* __restrict__ v1s, const float* __restrict__ v2s,
    const float* __restrict__ HW1p, const float* __restrict__ Hb1p,
    const float* __restrict__ HW2p, const float* __restrict__ Hb2p,
    const float* __restrict__ Wout, const float* __restrict__ bout,
    float* __restrict__ y)
{
  __shared__ float xin[2 * P_];
  __shared__ float h[P_];
  const int b = blockIdx.x;
  const int tid = threadIdx.x;
  xin[tid] = v1s[(long)b * P_ + tid];
  xin[P_ + tid] = v2s[(long)b * P_ + tid];
  __syncthreads();
  float acc = Hb1p[tid];
  for (int e = 0; e < 2 * P_; ++e) acc += xin[e] * HW1p[(long)e * P_ + tid];
  h[tid] = fmaxf(acc, 0.0f);
  __syncthreads();
  float acc2 = Hb2p[tid];
  for (int e = 0; e < P_; ++e) acc2 += h[e] * HW2p[(long)e * P_ + tid];
  const float h2 = fmaxf(acc2, 0.0f);
  __syncthreads();
  xin[tid] = h2;
  __syncthreads();
  if (tid < C_) {
    float a = bout[tid];
    for (int d = 0; d < D_; ++d) a += xin[d] * Wout[d * C_ + tid];
    y[(long)b * C_ + tid] = a;
  }
}

// ---------------- launch ----------------
extern "C" void kernel_launch(void* const* d_in, const int* in_sizes, int n_in,
                              void* d_out, int out_size, void* d_ws, size_t ws_size,
                              hipStream_t stream)
{
  const int*   x1    = (const int*)d_in[0];
  const int*   x2    = (const int*)d_in[1];
  const int*   len1  = (const int*)d_in[2];
  const int*   len2  = (const int*)d_in[3];
  const float* emb   = (const float*)d_in[4];
  const float* Wproj = (const float*)d_in[5];
  const float* FW1   = (const float*)d_in[6];
  const float* Fb1   = (const float*)d_in[7];
  const float* FW2   = (const float*)d_in[8];
  const float* Fb2   = (const float*)d_in[9];
  const float* GW1   = (const float*)d_in[10];
  const float* Gb1   = (const float*)d_in[11];
  const float* GW2   = (const float*)d_in[12];
  const float* Gb2   = (const float*)d_in[13];
  const float* HW1   = (const float*)d_in[14];
  const float* Hb1   = (const float*)d_in[15];
  const float* HW2   = (const float*)d_in[16];
  const float* Hb2   = (const float*)d_in[17];
  const float* Wout  = (const float*)d_in[18];
  const float* bout  = (const float*)d_in[19];
  float* out = (float*)d_out;

  float* ws = (float*)d_ws;
  size_t o = 0;
  auto alloc = [&](size_t n) { float* p = ws + o; o += n; return p; };
  float* v12    = alloc((size_t)2 * B_ * P_);
  float* HW1p   = alloc((size_t)2 * P_ * P_);
  float* HW2p   = alloc((size_t)P_ * P_);
  float* biases = alloc((size_t)6 * 256);
  int* ids12  = (int*)alloc((size_t)2 * TOK_);
  int* lens12 = (int*)alloc(2 * B_);
  unsigned short* us = (unsigned short*)(ws + o);
  size_t uo = 0;
  auto ualloc = [&](size_t n) { unsigned short* p = us + uo; uo += n; return p; };
  unsigned short* x12b  = ualloc((size_t)2 * TOK_ * P_);
  unsigned short* f12b  = ualloc((size_t)2 * TOK_ * P_);
  unsigned short* ba12b = ualloc((size_t)2 * TOK_ * P_);
  unsigned short* x12T  = ualloc((size_t)2 * TOK_ * P_);
  unsigned short* WpT   = ualloc((size_t)P_ * 320);
  unsigned short* FW1T  = ualloc((size_t)P_ * P_);
  unsigned short* FW2T  = ualloc((size_t)P_ * P_);
  unsigned short* GW1T  = ualloc((size_t)P_ * 2 * P_);
  unsigned short* GW2T  = ualloc((size_t)P_ * P_);
  if (o * sizeof(float) + uo * sizeof(unsigned short) > ws_size) return;

  float* Fb1p = biases + 0;
  float* Fb2p = biases + 256;
  float* Gb1p = biases + 512;
  float* Gb2p = biases + 768;
  float* Hb1p = biases + 1024;
  float* Hb2p = biases + 1280;
  float* v1s = v12;
  float* v2s = v12 + (size_t)B_ * P_;

  // 1. all prep in one launch
  prep_all<<<2887, 256, 0, stream>>>(
      Wproj, FW1, FW2, GW1, GW2, HW1, HW2,
      Fb1, Fb2, Gb1, Gb2, Hb1, Hb2,
      x1, x2, len1, len2,
      WpT, FW1T, FW2T, GW1T, GW2T, HW1p, HW2p, biases, v12, ids12, lens12);

  // 2. merged projection (gather GEMM + fused embedding norm, K=320)
  proj_mfma<<<2 * TOK_ / 128, 512, 0, stream>>>(ids12, emb, WpT, x12b, 320);

  // 3. transposed projections for attend PV
  {
    dim3 grid(2 * B_, 4, 4);
    transpose_bf16<<<grid, 256, 0, stream>>>(x12b, x12T);
  }

  // 4. fused F MLP (both layers, 2*TOK rows, 64-row tiles)
  fused_mlp<0, false><<<2 * TOK_ / 64, 512, 0, stream>>>(
      x12b, nullptr, FW1T, Fb1p, FW2T, Fb2p, f12b, nullptr, nullptr, P_);

  // 5. fused attention, both directions (64-row tiles)
  {
    dim3 grid(S_ / 64, B_, 2);
    attend_fused<<<grid, 512, 0, stream>>>(f12b, x12T, lens12, ba12b);
  }

  // 6. fused G MLP + masked aggregation (64-row tiles)
  fused_mlp<2, true><<<2 * TOK_ / 64, 512, 0, stream>>>(
      x12b, ba12b, GW1T, Gb1p, GW2T, Gb2p, nullptr, v12, lens12, 2 * P_);

  // 7. head
  head_kernel<<<B_, 256, 0, stream>>>(v1s, v2s, HW1p, Hb1p, HW2p, Hb2p, Wout, bout, out);
}

// Round 9
// 364.137 us; speedup vs baseline: 3.4224x; 1.0831x over previous
//
#include <hip/hip_runtime.h>
#include <math.h>

#define B_ 128
#define S_ 256
#define V_ 50000
#define E_ 300
#define D_ 200
#define C_ 3
#define P_ 256            // padded D
#define TOK_ (B_*S_)      // 32768

typedef __attribute__((ext_vector_type(8))) short bf16x8;
typedef __attribute__((ext_vector_type(4))) float f32x4;

static __device__ __forceinline__ short f2bf(float f) {
  unsigned u = __builtin_bit_cast(unsigned, f);
  u += 0x7fffu + ((u >> 16) & 1u);   // RNE
  return (short)(u >> 16);
}

// ---------------- single fused prep kernel (weights, biases, ids, lens, zero) ----------------
__global__ __launch_bounds__(256) void prep_all(
    const float* __restrict__ Wproj, const float* __restrict__ FW1,
    const float* __restrict__ FW2, const float* __restrict__ GW1,
    const float* __restrict__ GW2, const float* __restrict__ HW1,
    const float* __restrict__ HW2,
    const float* __restrict__ Fb1, const float* __restrict__ Fb2,
    const float* __restrict__ Gb1, const float* __restrict__ Gb2,
    const float* __restrict__ Hb1, const float* __restrict__ Hb2,
    const int* __restrict__ x1, const int* __restrict__ x2,
    const int* __restrict__ len1, const int* __restrict__ len2,
    unsigned short* __restrict__ WpT, unsigned short* __restrict__ FW1T,
    unsigned short* __restrict__ FW2T, unsigned short* __restrict__ GW1T,
    unsigned short* __restrict__ GW2T, float* __restrict__ HW1p,
    float* __restrict__ HW2p, float* __restrict__ biases,
    float* __restrict__ v12, int* __restrict__ ids12, int* __restrict__ lens12)
{
  const int blk = blockIdx.x;
  const int tid = threadIdx.x;
  if (blk < 320) {
    int idx = blk * 256 + tid;
    int n = idx / 320, k = idx - n * 320;
    WpT[idx] = (unsigned short)f2bf((k < E_ && n < D_) ? Wproj[k * D_ + n] : 0.0f);
  } else if (blk < 576) {
    int idx = (blk - 320) * 256 + tid;
    int n = idx >> 8, k = idx & 255;
    FW1T[idx] = (unsigned short)f2bf((k < D_ && n < D_) ? FW1[k * D_ + n] : 0.0f);
  } else if (blk < 832) {
    int idx = (blk - 576) * 256 + tid;
    int n = idx >> 8, k = idx & 255;
    FW2T[idx] = (unsigned short)f2bf((k < D_ && n < D_) ? FW2[k * D_ + n] : 0.0f);
  } else if (blk < 1088) {
    int idx = (blk - 832) * 256 + tid;
    int n = idx >> 8, k = idx & 255;
    GW2T[idx] = (unsigned short)f2bf((k < D_ && n < D_) ? GW2[k * D_ + n] : 0.0f);
  } else if (blk < 1600) {
    int idx = (blk - 1088) * 256 + tid;
    int n = idx >> 9, k = idx & 511;
    int sk = (k < 256) ? ((k < D_) ? k : -1) : (((k - 256) < D_) ? (D_ + k - 256) : -1);
    GW1T[idx] = (unsigned short)f2bf((sk >= 0 && n < D_) ? GW1[sk * D_ + n] : 0.0f);
  } else if (blk < 2112) {
    int idx = (blk - 1600) * 256 + tid;
    int r = idx >> 8, c = idx & 255;
    int sr = (r < D_) ? r : ((r >= 256 && r < 256 + D_) ? (r - 56) : -1);
    HW1p[idx] = (sr >= 0 && c < D_) ? HW1[sr * D_ + c] : 0.0f;
  } else if (blk < 2368) {
    int idx = (blk - 2112) * 256 + tid;
    int r = idx >> 8, c = idx & 255;
    HW2p[idx] = (r < D_ && c < D_) ? HW2[r * D_ + c] : 0.0f;
  } else if (blk < 2374) {
    int j = blk - 2368;
    const float* src = (j == 0) ? Fb1 : (j == 1) ? Fb2 : (j == 2) ? Gb1
                      : (j == 3) ? Gb2 : (j == 4) ? Hb1 : Hb2;
    biases[j * 256 + tid] = (tid < D_) ? src[tid] : 0.0f;
  } else if (blk < 2630) {
    v12[(blk - 2374) * 256 + tid] = 0.0f;
  } else if (blk < 2886) {
    int idx = (blk - 2630) * 256 + tid;
    ids12[idx] = (idx < TOK_) ? x1[idx] : x2[idx - TOK_];
  } else {
    if (tid < B_) lens12[tid] = len1[tid];
    else if (tid < 2 * B_) lens12[tid] = len2[tid - B_];
  }
}

// ---------------- batch transpose bf16: out[b][d][s] = in[b][s][d] ----------------
__global__ __launch_bounds__(256) void transpose_bf16(
    const unsigned short* __restrict__ in, unsigned short* __restrict__ outp) {
  __shared__ unsigned short t[64][66];
  const int b = blockIdx.x;
  const int r0 = blockIdx.y * 64, c0 = blockIdx.z * 64;
  const unsigned short* src = in + (long)b * S_ * P_;
  unsigned short* dst = outp + (long)b * P_ * S_;
  const int tx = threadIdx.x & 63, ty = threadIdx.x >> 6;
  #pragma unroll
  for (int i = 0; i < 16; ++i)
    t[ty * 16 + i][tx] = src[(long)(r0 + ty * 16 + i) * P_ + c0 + tx];
  __syncthreads();
  #pragma unroll
  for (int i = 0; i < 16; ++i)
    dst[(long)(c0 + ty * 16 + i) * S_ + r0 + tx] = t[tx][ty * 16 + i];
}

// ---------------- projection GEMM (gather; norm accumulated DURING staging) ----------------
// 512 threads, 128-row tile. A = bf16(emb[ids[t]]) unnormalized; accumulator scaled by
// invn in the epilogue ((emb@W)*inv == (emb*inv)@W up to rounding placement).
__global__ __launch_bounds__(512) void proj_mfma(
    const int* __restrict__ ids, const float* __restrict__ emb,
    const unsigned short* __restrict__ WT,
    unsigned short* __restrict__ outp, int K)
{
  __shared__ unsigned short As[128 * 32];
  __shared__ unsigned short Bs[256 * 32];
  __shared__ float invn_s[128];
  const int tid = threadIdx.x;
  const int lane = tid & 63;
  const int w = tid >> 6;
  const int wr = w >> 2, wc = w & 3;
  const long t0 = (long)blockIdx.x * 128;
  const int g = lane >> 4, ln = lane & 15;

  f32x4 acc[4][4];
  #pragma unroll
  for (int i = 0; i < 4; ++i)
    #pragma unroll
    for (int j = 0; j < 4; ++j) acc[i][j] = (f32x4){0.f, 0.f, 0.f, 0.f};

  const int arow = tid >> 2, aks = tid & 3;
  const long abase = (long)ids[t0 + arow] * E_;
  float ss = 0.0f;   // partial sum of squares for row arow (this lane's k-slice)

  for (int k0 = 0; k0 < K; k0 += 32) {
    {
      const int kb = k0 + aks * 8;
      short tmp[8];
      #pragma unroll
      for (int i = 0; i < 8; ++i) {
        const int k = kb + i;
        float v = (k < E_) ? emb[abase + k] : 0.0f;
        ss += v * v;
        tmp[i] = f2bf(v);
      }
      bf16x8 v8;
      #pragma unroll
      for (int i = 0; i < 8; ++i) v8[i] = tmp[i];
      const int slot = aks ^ ((arow >> 1) & 3);
      *(bf16x8*)&As[arow * 32 + slot * 8] = v8;
    }
    #pragma unroll
    for (int cc = 0; cc < 2; ++cc) {
      const int c = tid + cc * 512;
      const int col = c >> 2, ks = c & 3;
      bf16x8 v = *(const bf16x8*)(WT + (long)col * K + k0 + ks * 8);
      const int slot = ks ^ ((col >> 1) & 3);
      *(bf16x8*)&Bs[col * 32 + slot * 8] = v;
    }
    __syncthreads();
    bf16x8 af[4], bfr[4];
    #pragma unroll
    for (int fr = 0; fr < 4; ++fr) {
      const int row = wr * 64 + fr * 16 + ln;
      af[fr] = *(const bf16x8*)&As[row * 32 + ((g ^ ((row >> 1) & 3)) * 8)];
    }
    #pragma unroll
    for (int fc = 0; fc < 4; ++fc) {
      const int col = wc * 64 + fc * 16 + ln;
      bfr[fc] = *(const bf16x8*)&Bs[col * 32 + ((g ^ ((col >> 1) & 3)) * 8)];
    }
    #pragma unroll
    for (int fr = 0; fr < 4; ++fr)
      #pragma unroll
      for (int fc = 0; fc < 4; ++fc)
        acc[fr][fc] = __builtin_amdgcn_mfma_f32_16x16x32_bf16(af[fr], bfr[fc], acc[fr][fc], 0, 0, 0);
    __syncthreads();
  }

  // reduce ss over the 4 lanes of each row (lanes arow*4+aks are adjacent) -> invn
  ss += __shfl_xor(ss, 1, 64);
  ss += __shfl_xor(ss, 2, 64);
  if (aks == 0) invn_s[arow] = 1.0f / sqrtf(ss);
  __syncthreads();

  const int g4 = g * 4;
  #pragma unroll
  for (int fc = 0; fc < 4; ++fc) {
    const int col = wc * 64 + fc * 16 + ln;
    #pragma unroll
    for (int fr = 0; fr < 4; ++fr) {
      const int rl = wr * 64 + fr * 16 + g4;
      const long rbase = t0 + rl;
      #pragma unroll
      for (int r = 0; r < 4; ++r)
        outp[(rbase + r) * P_ + col] = (unsigned short)f2bf(acc[fr][fc][r] * invn_s[rl + r]);
    }
  }
}

// ---------------- fused two-layer MLP: 64-row tile, 512 threads (8 waves 1x8) ----------------
// out = relu(relu(A@W1+b1)@W2+b2); MODE1 0: A=A1 (K1=256); MODE1 2: A=concat(A1,A2) (K1=512).
// AGG: masked column-sum -> atomicAdd aggOut.
template<int MODE1, bool AGG>
__global__ __launch_bounds__(512) void fused_mlp(
    const unsigned short* __restrict__ A1, const unsigned short* __restrict__ A2,
    const unsigned short* __restrict__ W1T, const float* __restrict__ b1,
    const unsigned short* __restrict__ W2T, const float* __restrict__ b2,
    unsigned short* __restrict__ outp, float* __restrict__ aggOut,
    const int* __restrict__ lens, int K1)
{
  __shared__ unsigned short As[64 * 32];
  __shared__ unsigned short Bs[256 * 32];
  __shared__ unsigned short Hs[64 * 256];
  const int tid = threadIdx.x;
  const int lane = tid & 63;
  const int w = tid >> 6;               // 0..7 (col groups of 32)
  const long t0 = (long)blockIdx.x * 64;
  const int g = lane >> 4, ln = lane & 15;
  const int g4 = g * 4;

  f32x4 acc[4][2];
  #pragma unroll
  for (int i = 0; i < 4; ++i)
    #pragma unroll
    for (int j = 0; j < 2; ++j) acc[i][j] = (f32x4){0.f, 0.f, 0.f, 0.f};

  // ---- stage 1: H = relu(A @ W1 + b1)
  for (int k0 = 0; k0 < K1; k0 += 32) {
    if (tid < 256) {
      const int arow = tid >> 2, aks = tid & 3;
      bf16x8 v;
      if (MODE1 == 2) {
        const unsigned short* src = (k0 < P_) ? (A1 + (t0 + arow) * P_ + k0)
                                              : (A2 + (t0 + arow) * P_ + (k0 - P_));
        v = *(const bf16x8*)(src + aks * 8);
      } else {
        v = *(const bf16x8*)(A1 + (t0 + arow) * P_ + k0 + aks * 8);
      }
      const int slot = aks ^ ((arow >> 1) & 3);
      *(bf16x8*)&As[arow * 32 + slot * 8] = v;
    }
    #pragma unroll
    for (int cc = 0; cc < 2; ++cc) {
      const int c = tid + cc * 512;
      const int col = c >> 2, ks = c & 3;
      bf16x8 v = *(const bf16x8*)(W1T + (long)col * K1 + k0 + ks * 8);
      const int slot = ks ^ ((col >> 1) & 3);
      *(bf16x8*)&Bs[col * 32 + slot * 8] = v;
    }
    __syncthreads();
    bf16x8 af[4], bfr[2];
    #pragma unroll
    for (int fr = 0; fr < 4; ++fr) {
      const int row = fr * 16 + ln;
      af[fr] = *(const bf16x8*)&As[row * 32 + ((g ^ ((row >> 1) & 3)) * 8)];
    }
    #pragma unroll
    for (int fc = 0; fc < 2; ++fc) {
      const int col = w * 32 + fc * 16 + ln;
      bfr[fc] = *(const bf16x8*)&Bs[col * 32 + ((g ^ ((col >> 1) & 3)) * 8)];
    }
    #pragma unroll
    for (int fr = 0; fr < 4; ++fr)
      #pragma unroll
      for (int fc = 0; fc < 2; ++fc)
        acc[fr][fc] = __builtin_amdgcn_mfma_f32_16x16x32_bf16(af[fr], bfr[fc], acc[fr][fc], 0, 0, 0);
    __syncthreads();
  }

  // write H to LDS (bf16, A-tile swizzle)
  #pragma unroll
  for (int fc = 0; fc < 2; ++fc) {
    const int col = w * 32 + fc * 16 + ln;
    const float bb = b1[col];
    #pragma unroll
    for (int fr = 0; fr < 4; ++fr) {
      #pragma unroll
      for (int r = 0; r < 4; ++r) {
        const int lr = fr * 16 + g4 + r;
        const float v = fmaxf(acc[fr][fc][r] + bb, 0.0f);
        Hs[lr * 256 + ((col & ~31) | ((((col >> 3) & 3) ^ ((lr >> 1) & 3)) << 3) | (col & 7))] =
            (unsigned short)f2bf(v);
      }
    }
  }

  // ---- stage 2: O = relu(H @ W2 + b2)
  f32x4 acc2[4][2];
  #pragma unroll
  for (int i = 0; i < 4; ++i)
    #pragma unroll
    for (int j = 0; j < 2; ++j) acc2[i][j] = (f32x4){0.f, 0.f, 0.f, 0.f};

  for (int k0 = 0; k0 < 256; k0 += 32) {
    #pragma unroll
    for (int cc = 0; cc < 2; ++cc) {
      const int c = tid + cc * 512;
      const int col = c >> 2, ks = c & 3;
      bf16x8 v = *(const bf16x8*)(W2T + (long)col * 256 + k0 + ks * 8);
      const int slot = ks ^ ((col >> 1) & 3);
      *(bf16x8*)&Bs[col * 32 + slot * 8] = v;
    }
    __syncthreads();   // covers H writes on first iteration
    bf16x8 af[4], bfr[2];
    #pragma unroll
    for (int fr = 0; fr < 4; ++fr) {
      const int row = fr * 16 + ln;
      af[fr] = *(const bf16x8*)&Hs[row * 256 + k0 + ((g ^ ((row >> 1) & 3)) * 8)];
    }
    #pragma unroll
    for (int fc = 0; fc < 2; ++fc) {
      const int col = w * 32 + fc * 16 + ln;
      bfr[fc] = *(const bf16x8*)&Bs[col * 32 + ((g ^ ((col >> 1) & 3)) * 8)];
    }
    #pragma unroll
    for (int fr = 0; fr < 4; ++fr)
      #pragma unroll
      for (int fc = 0; fc < 2; ++fc)
        acc2[fr][fc] = __builtin_amdgcn_mfma_f32_16x16x32_bf16(af[fr], bfr[fc], acc2[fr][fc], 0, 0, 0);
    __syncthreads();
  }

  // ---- epilogue
  if (AGG) {
    const int b = (int)(t0 >> 8);
    const int s0 = (int)(t0 & 255);
    const int len = lens[b];
    #pragma unroll
    for (int fc = 0; fc < 2; ++fc) {
      const int col = w * 32 + fc * 16 + ln;
      const float bb = b2[col];
      float sum = 0.0f;
      #pragma unroll
      for (int fr = 0; fr < 4; ++fr) {
        const int sbase = s0 + fr * 16 + g4;
        #pragma unroll
        for (int r = 0; r < 4; ++r) {
          if (sbase + r < len) sum += fmaxf(acc2[fr][fc][r] + bb, 0.0f);
        }
      }
      sum += __shfl_xor(sum, 16, 64);
      sum += __shfl_xor(sum, 32, 64);
      if (g == 0) atomicAdd(&aggOut[(long)b * P_ + col], sum);
    }
  } else {
    #pragma unroll
    for (int fc = 0; fc < 2; ++fc) {
      const int col = w * 32 + fc * 16 + ln;
      const float bb = b2[col];
      #pragma unroll
      for (int fr = 0; fr < 4; ++fr) {
        const long rbase = t0 + fr * 16 + g4;
        #pragma unroll
        for (int r = 0; r < 4; ++r)
          outp[(rbase + r) * P_ + col] = (unsigned short)f2bf(fmaxf(acc2[fr][fc][r] + bb, 0.0f));
      }
    }
  }
}

// ---------------- fused attention: 64-row tile, 512 threads (8 waves 1x8) ----------------
// blockIdx.z: z=0 beta (rows=f1), z=1 alpha (operands swapped).
__global__ __launch_bounds__(512) void attend_fused(
    const unsigned short* __restrict__ f12, const unsigned short* __restrict__ x12T,
    const int* __restrict__ lens12, unsigned short* __restrict__ out12)
{
  __shared__ unsigned short As[64 * 32];
  __shared__ unsigned short Bs[256 * 32];
  __shared__ unsigned short Pt[64 * 256];
  __shared__ float redmax[64][8];
  __shared__ float redsum[64][8];

  const int tid = threadIdx.x;
  const int lane = tid & 63;
  const int w = tid >> 6;               // 0..7 (col groups of 32)
  const int b = blockIdx.y;
  const int z = blockIdx.z;
  const int i0 = blockIdx.x * 64;
  const int g = lane >> 4, ln = lane & 15;
  const int g4 = g * 4;

  const unsigned short* Afeat = f12 + (size_t)z * TOK_ * P_;
  const unsigned short* Bfeat = f12 + (size_t)(1 - z) * TOK_ * P_;
  const unsigned short* XT    = x12T + (size_t)(1 - z) * TOK_ * P_;
  unsigned short* outp        = out12 + (size_t)z * TOK_ * P_;
  const int l1 = lens12[z * B_ + b];
  const int l2 = lens12[(1 - z) * B_ + b];

  const unsigned short* Arows = Afeat + ((long)b * S_ + i0) * P_;
  const unsigned short* Brows = Bfeat + (long)b * S_ * P_;

  f32x4 acc[4][2];
  #pragma unroll
  for (int i = 0; i < 4; ++i)
    #pragma unroll
    for (int j = 0; j < 2; ++j) acc[i][j] = (f32x4){0.f, 0.f, 0.f, 0.f};

  // ---- phase 1: S = A @ B^T
  for (int k0 = 0; k0 < P_; k0 += 32) {
    if (tid < 256) {
      const int arow = tid >> 2, aks = tid & 3;
      bf16x8 v = *(const bf16x8*)(Arows + (long)arow * P_ + k0 + aks * 8);
      const int slot = aks ^ ((arow >> 1) & 3);
      *(bf16x8*)&As[arow * 32 + slot * 8] = v;
    }
    #pragma unroll
    for (int cc = 0; cc < 2; ++cc) {
      const int c = tid + cc * 512;
      const int col = c >> 2, ks = c & 3;
      bf16x8 v = *(const bf16x8*)(Brows + (long)col * P_ + k0 + ks * 8);
      const int slot = ks ^ ((col >> 1) & 3);
      *(bf16x8*)&Bs[col * 32 + slot * 8] = v;
    }
    __syncthreads();
    bf16x8 af[4], bfr[2];
    #pragma unroll
    for (int fr = 0; fr < 4; ++fr) {
      const int row = fr * 16 + ln;
      af[fr] = *(const bf16x8*)&As[row * 32 + ((g ^ ((row >> 1) & 3)) * 8)];
    }
    #pragma unroll
    for (int fc = 0; fc < 2; ++fc) {
      const int col = w * 32 + fc * 16 + ln;
      bfr[fc] = *(const bf16x8*)&Bs[col * 32 + ((g ^ ((col >> 1) & 3)) * 8)];
    }
    #pragma unroll
    for (int fr = 0; fr < 4; ++fr)
      #pragma unroll
      for (int fc = 0; fc < 2; ++fc)
        acc[fr][fc] = __builtin_amdgcn_mfma_f32_16x16x32_bf16(af[fr], bfr[fc], acc[fr][fc], 0, 0, 0);
    __syncthreads();
  }

  // ---- mask (multiplicative; masked entries keep exp(0) per reference)
  #pragma unroll
  for (int fc = 0; fc < 2; ++fc) {
    const int col = w * 32 + fc * 16 + ln;
    const float mj = (col < l2) ? 1.0f : 0.0f;
    #pragma unroll
    for (int fr = 0; fr < 4; ++fr) {
      #pragma unroll
      for (int r = 0; r < 4; ++r) {
        const int rowg = i0 + fr * 16 + g4 + r;
        acc[fr][fc][r] *= (rowg < l1) ? mj : 0.0f;
      }
    }
  }
  // per-wave (32-col) max -> LDS
  #pragma unroll
  for (int fr = 0; fr < 4; ++fr) {
    #pragma unroll
    for (int r = 0; r < 4; ++r) {
      float m = fmaxf(acc[fr][0][r], acc[fr][1][r]);
      m = fmaxf(m, __shfl_xor(m, 1, 64));
      m = fmaxf(m, __shfl_xor(m, 2, 64));
      m = fmaxf(m, __shfl_xor(m, 4, 64));
      m = fmaxf(m, __shfl_xor(m, 8, 64));
      if (ln == 0) redmax[fr * 16 + g4 + r][w] = m;
    }
  }
  __syncthreads();
  #pragma unroll
  for (int fr = 0; fr < 4; ++fr) {
    #pragma unroll
    for (int r = 0; r < 4; ++r) {
      const int lr = fr * 16 + g4 + r;
      const float4 a4 = *(const float4*)&redmax[lr][0];
      const float4 b4 = *(const float4*)&redmax[lr][4];
      const float m = fmaxf(fmaxf(fmaxf(a4.x, a4.y), fmaxf(a4.z, a4.w)),
                            fmaxf(fmaxf(b4.x, b4.y), fmaxf(b4.z, b4.w)));
      float s = 0.0f;
      #pragma unroll
      for (int fc = 0; fc < 2; ++fc) {
        const float e = __expf(acc[fr][fc][r] - m);
        acc[fr][fc][r] = e;
        s += e;
      }
      s += __shfl_xor(s, 1, 64);
      s += __shfl_xor(s, 2, 64);
      s += __shfl_xor(s, 4, 64);
      s += __shfl_xor(s, 8, 64);
      if (ln == 0) redsum[lr][w] = s;
    }
  }
  __syncthreads();
  // normalize + write P tile (bf16, swizzled)
  #pragma unroll
  for (int fr = 0; fr < 4; ++fr) {
    #pragma unroll
    for (int r = 0; r < 4; ++r) {
      const int lr = fr * 16 + g4 + r;
      const float4 a4 = *(const float4*)&redsum[lr][0];
      const float4 b4 = *(const float4*)&redsum[lr][4];
      const float inv = 1.0f / (a4.x + a4.y + a4.z + a4.w + b4.x + b4.y + b4.z + b4.w);
      #pragma unroll
      for (int fc = 0; fc < 2; ++fc) {
        const int col = w * 32 + fc * 16 + ln;
        Pt[lr * 256 + ((col & ~31) | ((((col >> 3) & 3) ^ ((lr >> 1) & 3)) << 3) | (col & 7))] =
            (unsigned short)f2bf(acc[fr][fc][r] * inv);
      }
    }
  }

  // ---- phase 2: out = P @ X
  f32x4 acc2[4][2];
  #pragma unroll
  for (int i = 0; i < 4; ++i)
    #pragma unroll
    for (int j = 0; j < 2; ++j) acc2[i][j] = (f32x4){0.f, 0.f, 0.f, 0.f};
  const unsigned short* XTb = XT + (long)b * P_ * S_;
  for (int k0 = 0; k0 < S_; k0 += 32) {
    #pragma unroll
    for (int cc = 0; cc < 2; ++cc) {
      const int c = tid + cc * 512;
      const int col = c >> 2, ks = c & 3;
      bf16x8 v = *(const bf16x8*)(XTb + (long)col * S_ + k0 + ks * 8);
      const int slot = ks ^ ((col >> 1) & 3);
      *(bf16x8*)&Bs[col * 32 + slot * 8] = v;
    }
    __syncthreads();   // first iteration also covers Pt writes
    bf16x8 af[4], bfr[2];
    #pragma unroll
    for (int fr = 0; fr < 4; ++fr) {
      const int row = fr * 16 + ln;
      af[fr] = *(const bf16x8*)&Pt[row * 256 + k0 + ((g ^ ((row >> 1) & 3)) * 8)];
    }
    #pragma unroll
    for (int fc = 0; fc < 2; ++fc) {
      const int col = w * 32 + fc * 16 + ln;
      bfr[fc] = *(const bf16x8*)&Bs[col * 32 + ((g ^ ((col >> 1) & 3)) * 8)];
    }
    #pragma unroll
    for (int fr = 0; fr < 4; ++fr)
      #pragma unroll
      for (int fc = 0; fc < 2; ++fc)
        acc2[fr][fc] = __builtin_amdgcn_mfma_f32_16x16x32_bf16(af[fr], bfr[fc], acc2[fr][fc], 0, 0, 0);
    __syncthreads();
  }

  #pragma unroll
  for (int fc = 0; fc < 2; ++fc) {
    const int col = w * 32 + fc * 16 + ln;
    #pragma unroll
    for (int fr = 0; fr < 4; ++fr) {
      const long rbase = (long)b * S_ + i0 + fr * 16 + g4;
      #pragma unroll
      for (int r = 0; r < 4; ++r)
        outp[(rbase + r) * P_ + col] = (unsigned short)f2bf(acc2[fr][fc][r]);
    }
  }
}

// ---------------- final head (fp32) ----------------
__global__ __launch_bounds__(256) void head_kernel(
    const float* __restrict__ v1s, const float* __restrict__ v2s,
    const float* __restrict__ HW1p, const float* __restrict__ Hb1p,
    const float* __restrict__ HW2p, const float* __restrict__ Hb2p,
    const float* __restrict__ Wout, const float* __restrict__ bout,
    float* __restrict__ y)
{
  __shared__ float xin[2 * P_];
  __shared__ float h[P_];
  const int b = blockIdx.x;
  const int tid = threadIdx.x;
  xin[tid] = v1s[(long)b * P_ + tid];
  xin[P_ + tid] = v2s[(long)b * P_ + tid];
  __syncthreads();
  float acc = Hb1p[tid];
  for (int e = 0; e < 2 * P_; ++e) acc += xin[e] * HW1p[(long)e * P_ + tid];
  h[tid] = fmaxf(acc, 0.0f);
  __syncthreads();
  float acc2 = Hb2p[tid];
  for (int e = 0; e < P_; ++e) acc2 += h[e] * HW2p[(long)e * P_ + tid];
  const float h2 = fmaxf(acc2, 0.0f);
  __syncthreads();
  xin[tid] = h2;
  __syncthreads();
  if (tid < C_) {
    float a = bout[tid];
    for (int d = 0; d < D_; ++d) a += xin[d] * Wout[d * C_ + tid];
    y[(long)b * C_ + tid] = a;
  }
}

// ---------------- launch ----------------
extern "C" void kernel_launch(void* const* d_in, const int* in_sizes, int n_in,
                              void* d_out, int out_size, void* d_ws, size_t ws_size,
                              hipStream_t stream)
{
  const int*   x1    = (const int*)d_in[0];
  const int*   x2    = (const int*)d_in[1];
  const int*   len1  = (const int*)d_in[2];
  const int*   len2  = (const int*)d_in[3];
  const float* emb   = (const float*)d_in[4];
  const float* Wproj = (const float*)d_in[5];
  const float* FW1   = (const float*)d_in[6];
  const float* Fb1   = (const float*)d_in[7];
  const float* FW2   = (const float*)d_in[8];
  const float* Fb2   = (const float*)d_in[9];
  const float* GW1   = (const float*)d_in[10];
  const float* Gb1   = (const float*)d_in[11];
  const float* GW2   = (const float*)d_in[12];
  const float* Gb2   = (const float*)d_in[13];
  const float* HW1   = (const float*)d_in[14];
  const float* Hb1   = (const float*)d_in[15];
  const float* HW2   = (const float*)d_in[16];
  const float* Hb2   = (const float*)d_in[17];
  const float* Wout  = (const float*)d_in[18];
  const float* bout  = (const float*)d_in[19];
  float* out = (float*)d_out;

  float* ws = (float*)d_ws;
  size_t o = 0;
  auto alloc = [&](size_t n) { float* p = ws + o; o += n; return p; };
  float* v12    = alloc((size_t)2 * B_ * P_);
  float* HW1p   = alloc((size_t)2 * P_ * P_);
  float* HW2p   = alloc((size_t)P_ * P_);
  float* biases = alloc((size_t)6 * 256);
  int* ids12  = (int*)alloc((size_t)2 * TOK_);
  int* lens12 = (int*)alloc(2 * B_);
  unsigned short* us = (unsigned short*)(ws + o);
  size_t uo = 0;
  auto ualloc = [&](size_t n) { unsigned short* p = us + uo; uo += n; return p; };
  unsigned short* x12b  = ualloc((size_t)2 * TOK_ * P_);
  unsigned short* f12b  = ualloc((size_t)2 * TOK_ * P_);
  unsigned short* ba12b = ualloc((size_t)2 * TOK_ * P_);
  unsigned short* x12T  = ualloc((size_t)2 * TOK_ * P_);
  unsigned short* WpT   = ualloc((size_t)P_ * 320);
  unsigned short* FW1T  = ualloc((size_t)P_ * P_);
  unsigned short* FW2T  = ualloc((size_t)P_ * P_);
  unsigned short* GW1T  = ualloc((size_t)P_ * 2 * P_);
  unsigned short* GW2T  = ualloc((size_t)P_ * P_);
  if (o * sizeof(float) + uo * sizeof(unsigned short) > ws_size) return;

  float* Fb1p = biases + 0;
  float* Fb2p = biases + 256;
  float* Gb1p = biases + 512;
  float* Gb2p = biases + 768;
  float* Hb1p = biases + 1024;
  float* Hb2p = biases + 1280;
  float* v1s = v12;
  float* v2s = v12 + (size_t)B_ * P_;

  // 1. all prep in one launch
  prep_all<<<2887, 256, 0, stream>>>(
      Wproj, FW1, FW2, GW1, GW2, HW1, HW2,
      Fb1, Fb2, Gb1, Gb2, Hb1, Hb2,
      x1, x2, len1, len2,
      WpT, FW1T, FW2T, GW1T, GW2T, HW1p, HW2p, biases, v12, ids12, lens12);

  // 2. merged projection (gather GEMM, norm fused into staging, K=320)
  proj_mfma<<<2 * TOK_ / 128, 512, 0, stream>>>(ids12, emb, WpT, x12b, 320);

  // 3. transposed projections for attend PV
  {
    dim3 grid(2 * B_, 4, 4);
    transpose_bf16<<<grid, 256, 0, stream>>>(x12b, x12T);
  }

  // 4. fused F MLP (both layers, 2*TOK rows, 64-row tiles)
  fused_mlp<0, false><<<2 * TOK_ / 64, 512, 0, stream>>>(
      x12b, nullptr, FW1T, Fb1p, FW2T, Fb2p, f12b, nullptr, nullptr, P_);

  // 5. fused attention, both directions (64-row tiles)
  {
    dim3 grid(S_ / 64, B_, 2);
    attend_fused<<<grid, 512, 0, stream>>>(f12b, x12T, lens12, ba12b);
  }

  // 6. fused G MLP + masked aggregation (64-row tiles)
  fused_mlp<2, true><<<2 * TOK_ / 64, 512, 0, stream>>>(
      x12b, ba12b, GW1T, Gb1p, GW2T, Gb2p, nullptr, v12, lens12, 2 * P_);

  // 7. head
  head_kernel<<<B_, 256, 0, stream>>>(v1s, v2s, HW1p, Hb1p, HW2p, Hb2p, Wout, bout, out);
}